// Round 1
// baseline (2918.445 us; speedup 1.0000x reference)
//
#include <hip/hip_runtime.h>
#include <hip/hip_bf16.h>

// ---------------- problem constants ----------------
#define BB   256   // batch
#define CC1  256   // conv1 out channels
#define NI   1152  // primary capsules
#define JD   10    // out capsules
#define OD   16    // out dim
#define DD   8     // primary dim

// ws layout (in floats)
static const size_t WT2_OFF = 0;                              // wT2: 20736*256
static const size_t WT1_OFF = WT2_OFF + 20736UL * 256;        // wT1: 81*256
static const size_t H_OFF   = WT1_OFF + 81UL * 256;           // h: 256*256*400
static const size_t PP_OFF  = H_OFF + 256UL * 256 * 400;      // p_part: 4*256*256*36
static const size_t U_OFF   = PP_OFF + 4UL * 256 * 256 * 36;  // u: 256*1152*8
static const size_t LGO_OFF = U_OFF + 256UL * 1152 * 8;       // logits: 256*1152*10
static const size_t SP_OFF  = LGO_OFF + 256UL * 1152 * 10;    // s_part: 36*256*160
static const size_t V_OFF   = SP_OFF + 36UL * 256 * 160;      // v: 256*160

// ---------------- weight transposes ----------------
// pc_w [oc][ic*81+t'] -> wT2 [t][oc], t = ic*81 + ky*9 + kx
__global__ __launch_bounds__(256) void k_transpose_w2(const float* __restrict__ pcw,
                                                      float* __restrict__ wT) {
    __shared__ float tile[64][65];
    int t0  = blockIdx.x * 64;   // 324 tiles over 20736
    int oc0 = blockIdx.y * 64;   // 4 tiles over 256
    int r = threadIdx.x >> 2;    // 0..63
    int p = threadIdx.x & 3;     // 0..3
    const float4* src = (const float4*)(pcw + (size_t)(oc0 + r) * 20736 + t0 + p * 16);
#pragma unroll
    for (int k = 0; k < 4; ++k) {
        float4 v = src[k];
        int c = p * 16 + k * 4;
        tile[r][c] = v.x; tile[r][c + 1] = v.y; tile[r][c + 2] = v.z; tile[r][c + 3] = v.w;
    }
    __syncthreads();
    float4* dst = (float4*)(wT + (size_t)(t0 + r) * 256 + oc0 + p * 16);
#pragma unroll
    for (int k = 0; k < 4; ++k) {
        int c = p * 16 + k * 4;
        dst[k] = make_float4(tile[c][r], tile[c + 1][r], tile[c + 2][r], tile[c + 3][r]);
    }
}

// conv1_w [oc][81] -> wT1 [t][oc]
__global__ void k_transpose_w1(const float* __restrict__ w, float* __restrict__ wT) {
    int t  = blockIdx.x;    // 0..80
    int oc = threadIdx.x;   // 0..255
    wT[t * 256 + oc] = w[oc * 81 + t];
}

// ---------------- conv1 + relu ----------------
// lanes = oc (block covers 256 oc), each thread computes 2 output rows x 20 cols.
// x rows are block-uniform -> scalar loads.
__global__ __launch_bounds__(256) void k_conv1(const float* __restrict__ x,
                                               const float* __restrict__ wT1,
                                               const float* __restrict__ bias,
                                               float* __restrict__ h) {
    int b  = blockIdx.y;    // 256
    int rp = blockIdx.x;    // 10 row-pairs
    int oc = threadIdx.x;   // 256
    int oy0 = rp * 2;
    const float* xb = x + (size_t)b * 784;
    float bv = bias[oc];
    float acc0[20], acc1[20];
#pragma unroll
    for (int i = 0; i < 20; ++i) { acc0[i] = bv; acc1[i] = bv; }
    for (int ky = 0; ky < 9; ++ky) {
        const float* r0 = xb + (oy0 + ky) * 28;
        const float* r1 = r0 + 28;
        float x0[28], x1[28];
#pragma unroll
        for (int c = 0; c < 28; ++c) { x0[c] = r0[c]; x1[c] = r1[c]; }
#pragma unroll
        for (int kx = 0; kx < 9; ++kx) {
            float w = wT1[(ky * 9 + kx) * 256 + oc];
#pragma unroll
            for (int px = 0; px < 20; ++px) {
                acc0[px] += x0[px + kx] * w;
                acc1[px] += x1[px + kx] * w;
            }
        }
    }
    float* hp = h + ((size_t)(b * 256 + oc) * 20 + oy0) * 20;
#pragma unroll
    for (int q = 0; q < 5; ++q) {
        ((float4*)hp)[q] = make_float4(fmaxf(acc0[q * 4], 0.f), fmaxf(acc0[q * 4 + 1], 0.f),
                                       fmaxf(acc0[q * 4 + 2], 0.f), fmaxf(acc0[q * 4 + 3], 0.f));
        ((float4*)(hp + 20))[q] = make_float4(fmaxf(acc1[q * 4], 0.f), fmaxf(acc1[q * 4 + 1], 0.f),
                                              fmaxf(acc1[q * 4 + 2], 0.f), fmaxf(acc1[q * 4 + 3], 0.f));
    }
}

// ---------------- primary caps conv (stride 2), split-K partials ----------------
// grid (64 bgroups, 4 octiles, 4 ksplits); block 256 = 4 waves (wave = b), lane = oc_local.
// h rows are wave-uniform -> scalar loads feed v_fmac as SGPR operand.
__global__ __launch_bounds__(256) void k_conv2(const float* __restrict__ h,
                                               const float* __restrict__ wT2,
                                               float* __restrict__ pp) {
    int bg  = blockIdx.x;   // 64
    int oct = blockIdx.y;   // 4
    int ks  = blockIdx.z;   // 4
    int lane = threadIdx.x & 63;
    int wl = __builtin_amdgcn_readfirstlane((int)(threadIdx.x >> 6));
    int b  = bg * 4 + wl;
    int oc = oct * 64 + lane;
    float acc[36];
#pragma unroll
    for (int i = 0; i < 36; ++i) acc[i] = 0.f;
    int ic0 = ks * 64;
    for (int ic = ic0; ic < ic0 + 64; ++ic) {
        const float* hb = h + (size_t)(b * 256 + ic) * 400;
        for (int ky = 0; ky < 9; ++ky) {
            const float* wp = wT2 + (size_t)(ic * 81 + ky * 9) * 256 + oc;
            float w9[9];
#pragma unroll
            for (int kx = 0; kx < 9; ++kx) w9[kx] = wp[kx * 256];
            for (int py = 0; py < 6; ++py) {
                const float* hr = hb + (2 * py + ky) * 20;
                float hx[20];
#pragma unroll
                for (int c = 0; c < 20; ++c) hx[c] = hr[c];
#pragma unroll
                for (int px = 0; px < 6; ++px) {
#pragma unroll
                    for (int kx = 0; kx < 9; ++kx)
                        acc[py * 6 + px] += hx[2 * px + kx] * w9[kx];
                }
            }
        }
    }
    float* dst = pp + ((size_t)(ks * 256 + b) * 256 + oc) * 36;
#pragma unroll
    for (int q = 0; q < 9; ++q)
        ((float4*)dst)[q] = make_float4(acc[q * 4], acc[q * 4 + 1], acc[q * 4 + 2], acc[q * 4 + 3]);
}

// ---------------- sum partials + bias + primary squash -> u[b][i][d] ----------------
__global__ __launch_bounds__(256) void k_sum_squash(const float* __restrict__ pp,
                                                    const float* __restrict__ bias,
                                                    float* __restrict__ u) {
    __shared__ float s[9216];
    int b = blockIdx.x;
    for (int n = threadIdx.x; n < 9216; n += 256) {
        float a = pp[(size_t)(0 * 256 + b) * 9216 + n] + pp[(size_t)(1 * 256 + b) * 9216 + n] +
                  pp[(size_t)(2 * 256 + b) * 9216 + n] + pp[(size_t)(3 * 256 + b) * 9216 + n];
        a += bias[n / 36];
        s[n] = a;
    }
    __syncthreads();
    for (int i = threadIdx.x; i < NI; i += 256) {
        int cap = i / 36, px = i % 36;
        float p[8];
        float sq = 0.f;
#pragma unroll
        for (int d = 0; d < 8; ++d) { p[d] = s[(cap * 8 + d) * 36 + px]; sq += p[d] * p[d]; }
        float scale = sq / ((1.0f + sq) * sqrtf(sq + 1e-8f));
        float* up = u + (size_t)(b * NI + i) * 8;
        ((float4*)up)[0] = make_float4(scale * p[0], scale * p[1], scale * p[2], scale * p[3]);
        ((float4*)up)[1] = make_float4(scale * p[4], scale * p[5], scale * p[6], scale * p[7]);
    }
}

// ---------------- routing: s-partials (softmax fused, u_hat recomputed) ----------------
// grid (36 i-tiles, 4 b-tiles); block 256 = 64 b_lanes x 4 o-groups (wave-uniform og -> W scalar loads)
__global__ __launch_bounds__(256) void k_route_s(const float* __restrict__ L,
                                                 const float* __restrict__ U,
                                                 const float* __restrict__ W,
                                                 float* __restrict__ SP) {
    __shared__ float LG[64][81];
    __shared__ float UC[64][65];
    int it = blockIdx.x;  // 36
    int bt = blockIdx.y;  // 4
    int b0 = bt * 64;
    int b_l = threadIdx.x & 63;
    int og = __builtin_amdgcn_readfirstlane((int)(threadIdx.x >> 6));
    int b_r = threadIdx.x >> 2, part = threadIdx.x & 3;
    float acc[10][4];
#pragma unroll
    for (int j = 0; j < 10; ++j)
#pragma unroll
        for (int o = 0; o < 4; ++o) acc[j][o] = 0.f;

    for (int c8 = 0; c8 < 4; ++c8) {
        int i0 = it * 32 + c8 * 8;
        {
            const float4* lsrc = (const float4*)(L + (size_t)(b0 + b_r) * 11520 + i0 * 10 + part * 20);
#pragma unroll
            for (int q = 0; q < 5; ++q) {
                float4 t = lsrc[q]; int c = part * 20 + q * 4;
                LG[b_r][c] = t.x; LG[b_r][c + 1] = t.y; LG[b_r][c + 2] = t.z; LG[b_r][c + 3] = t.w;
            }
            const float4* usrc = (const float4*)(U + (size_t)(b0 + b_r) * 9216 + i0 * 8 + part * 16);
#pragma unroll
            for (int q = 0; q < 4; ++q) {
                float4 t = usrc[q]; int c = part * 16 + q * 4;
                UC[b_r][c] = t.x; UC[b_r][c + 1] = t.y; UC[b_r][c + 2] = t.z; UC[b_r][c + 3] = t.w;
            }
        }
        __syncthreads();
        for (int li = 0; li < 8; ++li) {
            float lg[10];
#pragma unroll
            for (int j = 0; j < 10; ++j) lg[j] = LG[b_l][li * 10 + j];
            float m = lg[0];
#pragma unroll
            for (int j = 1; j < 10; ++j) m = fmaxf(m, lg[j]);
            float e[10], ssum = 0.f;
#pragma unroll
            for (int j = 0; j < 10; ++j) { e[j] = __expf(lg[j] - m); ssum += e[j]; }
            float inv = 1.0f / ssum;
            float u8[8];
#pragma unroll
            for (int d = 0; d < 8; ++d) u8[d] = UC[b_l][li * 8 + d];
            const float* Wb = W + (size_t)(i0 + li) * 1280 + og * 4;
#pragma unroll
            for (int j = 0; j < 10; ++j) {
                float cj = e[j] * inv;
#pragma unroll
                for (int d = 0; d < 8; ++d) {
                    const float* wp = Wb + (d * 10 + j) * 16;
                    float f = cj * u8[d];
                    acc[j][0] += f * wp[0]; acc[j][1] += f * wp[1];
                    acc[j][2] += f * wp[2]; acc[j][3] += f * wp[3];
                }
            }
        }
        __syncthreads();
    }
    float* sp = SP + ((size_t)it * 256 + (b0 + b_l)) * 160 + og * 4;
#pragma unroll
    for (int j = 0; j < 10; ++j)
        *(float4*)(sp + j * 16) = make_float4(acc[j][0], acc[j][1], acc[j][2], acc[j][3]);
}

// ---------------- routing: reduce partials + squash -> v ----------------
__global__ __launch_bounds__(256) void k_route_v(const float* __restrict__ SP,
                                                 float* __restrict__ vout) {
    int n = blockIdx.x * 256 + threadIdx.x;  // 40960
    float ssum = 0.f;
#pragma unroll
    for (int t = 0; t < 36; ++t) ssum += SP[(size_t)t * 40960 + n];
    float sq = ssum * ssum;
    float tot = sq;
#pragma unroll
    for (int mask = 1; mask < 16; mask <<= 1) tot += __shfl_xor(tot, mask, 64);
    float scale = tot / ((1.0f + tot) * sqrtf(tot + 1e-8f));
    vout[n] = scale * ssum;
}

// ---------------- routing: agreement update b_logits += <u_hat, v> ----------------
__global__ __launch_bounds__(256) void k_route_agree(float* __restrict__ L,
                                                     const float* __restrict__ U,
                                                     const float* __restrict__ W,
                                                     const float* __restrict__ V) {
    __shared__ float LG[64][81];
    __shared__ float UC[64][65];
    __shared__ float VT[80][65];
    int it = blockIdx.x, bt = blockIdx.y;
    int b0 = bt * 64;
    int b_l = threadIdx.x & 63;
    int ig = __builtin_amdgcn_readfirstlane((int)(threadIdx.x >> 6));
    int b_r = threadIdx.x >> 2, part = threadIdx.x & 3;

    for (int jc = 0; jc < 2; ++jc) {
        __syncthreads();
        {   // stage half of v, transposed
            const float4* vsrc = (const float4*)(V + (size_t)(b0 + b_r) * 160 + jc * 80 + part * 20);
#pragma unroll
            for (int q = 0; q < 5; ++q) {
                float4 vv = vsrc[q];
                int jo = part * 20 + q * 4;
                VT[jo][b_r] = vv.x; VT[jo + 1][b_r] = vv.y; VT[jo + 2][b_r] = vv.z; VT[jo + 3][b_r] = vv.w;
            }
        }
        for (int c8 = 0; c8 < 4; ++c8) {
            int i0 = it * 32 + c8 * 8;
            __syncthreads();
            {
                const float4* lsrc = (const float4*)(L + (size_t)(b0 + b_r) * 11520 + i0 * 10 + part * 20);
#pragma unroll
                for (int q = 0; q < 5; ++q) {
                    float4 t = lsrc[q]; int c = part * 20 + q * 4;
                    LG[b_r][c] = t.x; LG[b_r][c + 1] = t.y; LG[b_r][c + 2] = t.z; LG[b_r][c + 3] = t.w;
                }
                const float4* usrc = (const float4*)(U + (size_t)(b0 + b_r) * 9216 + i0 * 8 + part * 16);
#pragma unroll
                for (int q = 0; q < 4; ++q) {
                    float4 t = usrc[q]; int c = part * 16 + q * 4;
                    UC[b_r][c] = t.x; UC[b_r][c + 1] = t.y; UC[b_r][c + 2] = t.z; UC[b_r][c + 3] = t.w;
                }
            }
            __syncthreads();
            float u8a[8], u8b[8];
#pragma unroll
            for (int d = 0; d < 8; ++d) {
                u8a[d] = UC[b_l][(ig * 2) * 8 + d];
                u8b[d] = UC[b_l][(ig * 2 + 1) * 8 + d];
            }
            int ia = i0 + ig * 2, ib2 = ia + 1;
#pragma unroll
            for (int jj = 0; jj < 5; ++jj) {
                int j = jc * 5 + jj;
                float v16[16];
#pragma unroll
                for (int o = 0; o < 16; ++o) v16[o] = VT[jj * 16 + o][b_l];
                const float* W0 = W + (size_t)ia * 1280 + j * 16;
                const float* W1 = W + (size_t)ib2 * 1280 + j * 16;
                float a0 = 0.f, a1 = 0.f;
#pragma unroll
                for (int d = 0; d < 8; ++d) {
                    float wv0 = 0.f, wv1 = 0.f;
#pragma unroll
                    for (int o = 0; o < 16; ++o) {
                        wv0 += W0[d * 160 + o] * v16[o];
                        wv1 += W1[d * 160 + o] * v16[o];
                    }
                    a0 += u8a[d] * wv0; a1 += u8b[d] * wv1;
                }
                LG[b_l][(ig * 2) * 10 + j] += a0;
                LG[b_l][(ig * 2 + 1) * 10 + j] += a1;
            }
            __syncthreads();
            {
                float4* ldst = (float4*)(L + (size_t)(b0 + b_r) * 11520 + i0 * 10 + part * 20);
#pragma unroll
                for (int q = 0; q < 5; ++q) {
                    int c = part * 20 + q * 4;
                    ldst[q] = make_float4(LG[b_r][c], LG[b_r][c + 1], LG[b_r][c + 2], LG[b_r][c + 3]);
                }
            }
        }
    }
}

// ---------------- launcher ----------------
extern "C" void kernel_launch(void* const* d_in, const int* in_sizes, int n_in,
                              void* d_out, int out_size, void* d_ws, size_t ws_size,
                              hipStream_t stream) {
    (void)in_sizes; (void)n_in; (void)out_size; (void)ws_size;
    const float* x   = (const float*)d_in[0];
    const float* c1w = (const float*)d_in[1];
    const float* c1b = (const float*)d_in[2];
    const float* pcw = (const float*)d_in[3];
    const float* pcb = (const float*)d_in[4];
    const float* Wd  = (const float*)d_in[5];
    float* out = (float*)d_out;
    float* ws  = (float*)d_ws;

    float* wT2 = ws + WT2_OFF;
    float* wT1 = ws + WT1_OFF;
    float* h   = ws + H_OFF;
    float* pp  = ws + PP_OFF;
    float* u   = ws + U_OFF;
    float* lg  = ws + LGO_OFF;
    float* sp  = ws + SP_OFF;
    float* v   = ws + V_OFF;

    hipMemsetAsync(lg, 0, (size_t)256 * 1152 * 10 * sizeof(float), stream);

    k_transpose_w2<<<dim3(324, 4), 256, 0, stream>>>(pcw, wT2);
    k_transpose_w1<<<81, 256, 0, stream>>>(c1w, wT1);
    k_conv1<<<dim3(10, 256), 256, 0, stream>>>(x, wT1, c1b, h);
    k_conv2<<<dim3(64, 4, 4), 256, 0, stream>>>(h, wT2, pp);
    k_sum_squash<<<256, 256, 0, stream>>>(pp, pcb, u);

    for (int itr = 0; itr < 3; ++itr) {
        k_route_s<<<dim3(36, 4), 256, 0, stream>>>(lg, u, Wd, sp);
        k_route_v<<<160, 256, 0, stream>>>(sp, (itr == 2) ? out : v);
        if (itr < 2)
            k_route_agree<<<dim3(36, 4), 256, 0, stream>>>(lg, u, Wd, v);
    }
}

// Round 2
// 1453.918 us; speedup vs baseline: 2.0073x; 2.0073x over previous
//
#include <hip/hip_runtime.h>
#include <hip/hip_bf16.h>

// ---------------- problem constants ----------------
#define NI   1152
// GEMM view of primary-caps conv: M=9216 (b,py,px), N=256 (oc), K=81 taps x 256 ic

typedef __attribute__((ext_vector_type(8))) short bf16x8;
typedef __attribute__((ext_vector_type(4))) float f32x4;

// ws layout (bytes)
static const size_t W4HI_OFF = 0;                         // 81*256*256 bf16
static const size_t W4LO_OFF = W4HI_OFF + 10616832UL;
static const size_t H2HI_OFF = W4LO_OFF + 10616832UL;     // 256*20*20*256 bf16
static const size_t H2LO_OFF = H2HI_OFF + 52428800UL;
static const size_t WT1_OFF  = H2LO_OFF + 52428800UL;     // 81*256 f32
static const size_t PP_OFF   = WT1_OFF + 82944UL;         // 4*9216*256 f32
static const size_t U_OFF    = PP_OFF + 37748736UL;       // 256*1152*8 f32
static const size_t LG_OFF   = U_OFF + 9437184UL;         // 256*1152*10 f32
static const size_t SP_OFF   = LG_OFF + 11796480UL;       // 36*256*160 f32
static const size_t V_OFF    = SP_OFF + 5898240UL;        // 256*160 f32

__device__ __forceinline__ unsigned short f2bf(float x) {
    unsigned u = __builtin_bit_cast(unsigned, x);
    u += 0x7fffu + ((u >> 16) & 1u);
    return (unsigned short)(u >> 16);
}
__device__ __forceinline__ float bf2f(unsigned short h) {
    return __builtin_bit_cast(float, (unsigned)h << 16);
}

#define GLD16(gsrc, ldst)                                                      \
    __builtin_amdgcn_global_load_lds(                                          \
        (__attribute__((address_space(1))) const void*)(gsrc),                 \
        (__attribute__((address_space(3))) void*)(ldst), 16, 0, 0)

// ---------------- weight prep: pc_w [oc][ic*81+tap] -> w4{hi,lo}[tap][oc][ic] ----------------
__global__ __launch_bounds__(256) void k_prep_w(const float* __restrict__ pcw,
                                                unsigned short* __restrict__ w4hi,
                                                unsigned short* __restrict__ w4lo) {
    __shared__ float sl[5184];
    int oc  = blockIdx.x;       // 256
    int ic0 = blockIdx.y * 64;  // 4 chunks
    const float* src = pcw + (size_t)oc * 20736 + (size_t)ic0 * 81;
    for (int j = threadIdx.x; j < 5184; j += 256) sl[j] = src[j];
    __syncthreads();
    for (int t = threadIdx.x; t < 5184; t += 256) {
        int tap = t >> 6, i = t & 63;
        float x = sl[i * 81 + tap];
        unsigned short hi = f2bf(x);
        size_t idx = (size_t)tap * 65536 + (size_t)oc * 256 + ic0 + i;
        w4hi[idx] = hi;
        w4lo[idx] = f2bf(x - bf2f(hi));
    }
}

// conv1_w [oc][81] -> wT1 [t][oc]
__global__ void k_transpose_w1(const float* __restrict__ w, float* __restrict__ wT) {
    int t = blockIdx.x, oc = threadIdx.x;
    wT[t * 256 + oc] = w[oc * 81 + t];
}

// ---------------- conv1 + relu -> h2{hi,lo}[b][y][x][oc] bf16 split ----------------
__global__ __launch_bounds__(256) void k_conv1(const float* __restrict__ x,
                                               const float* __restrict__ wT1,
                                               const float* __restrict__ bias,
                                               unsigned short* __restrict__ h2hi,
                                               unsigned short* __restrict__ h2lo) {
    int b  = blockIdx.y;    // 256
    int rp = blockIdx.x;    // 10 row-pairs
    int oc = threadIdx.x;   // 256
    int oy0 = rp * 2;
    const float* xb = x + (size_t)b * 784;
    float bv = bias[oc];
    float acc0[20], acc1[20];
#pragma unroll
    for (int i = 0; i < 20; ++i) { acc0[i] = bv; acc1[i] = bv; }
    for (int ky = 0; ky < 9; ++ky) {
        const float* r0 = xb + (oy0 + ky) * 28;
        const float* r1 = r0 + 28;
        float x0[28], x1[28];
#pragma unroll
        for (int c = 0; c < 28; ++c) { x0[c] = r0[c]; x1[c] = r1[c]; }
#pragma unroll
        for (int kx = 0; kx < 9; ++kx) {
            float w = wT1[(ky * 9 + kx) * 256 + oc];
#pragma unroll
            for (int px = 0; px < 20; ++px) {
                acc0[px] += x0[px + kx] * w;
                acc1[px] += x1[px + kx] * w;
            }
        }
    }
#pragma unroll
    for (int px = 0; px < 20; ++px) {
        float v0 = fmaxf(acc0[px], 0.f), v1 = fmaxf(acc1[px], 0.f);
        size_t i0 = (size_t)((b * 20 + oy0) * 20 + px) * 256 + oc;
        size_t i1 = (size_t)((b * 20 + oy0 + 1) * 20 + px) * 256 + oc;
        unsigned short h0 = f2bf(v0), h1 = f2bf(v1);
        h2hi[i0] = h0; h2lo[i0] = f2bf(v0 - bf2f(h0));
        h2hi[i1] = h1; h2lo[i1] = f2bf(v1 - bf2f(h1));
    }
}

// ---------------- primary caps conv as MFMA implicit GEMM (split-bf16, 3 passes) ----------------
// grid (72 m-tiles, 2 n-tiles, 4 ic-splits); block 256 = 4 waves; 128x128 tile, BK=32.
// LDS layout per operand: 4 k-chunk planes x 128 rows x 8 bf16 (16B per row-chunk).
__global__ __launch_bounds__(256, 2) void k_conv2_mfma(
    const unsigned short* __restrict__ h2hi, const unsigned short* __restrict__ h2lo,
    const unsigned short* __restrict__ w4hi, const unsigned short* __restrict__ w4lo,
    float* __restrict__ pp) {
    __shared__ unsigned short AsH[4096], AsL[4096], BsH[4096], BsL[4096];
    const int mt = blockIdx.x, nt = blockIdx.y, ks = blockIdx.z;
    const int l = threadIdx.x & 63;
    const int w = __builtin_amdgcn_readfirstlane((int)(threadIdx.x >> 6));
    const int wm = w >> 1, wn = w & 1;

    // per-lane staging source rows (element offsets)
    size_t gArow[2], gBrow[2];
#pragma unroll
    for (int q = 0; q < 2; ++q) {
        int m = mt * 128 + q * 64 + l;
        int b = m / 36, r = m % 36;
        int py = r / 6, px = r % 6;
        gArow[q] = ((size_t)(b * 20 + 2 * py) * 20 + 2 * px) * 256;
        gBrow[q] = (size_t)(nt * 128 + q * 64 + l) * 256;
    }
    const int ic_base = ks * 64;

    f32x4 acc[4][4];
    const f32x4 z = {0.f, 0.f, 0.f, 0.f};
#pragma unroll
    for (int mi = 0; mi < 4; ++mi)
#pragma unroll
        for (int ni = 0; ni < 4; ++ni) acc[mi][ni] = z;

    const int ch = (l >> 4) * 1024;           // k-chunk plane (ushorts)
    const int am = (wm * 64 + (l & 15)) * 8;  // a-frag row offset
    const int bn = (wn * 64 + (l & 15)) * 8;  // b-frag row offset

    for (int tap = 0; tap < 81; ++tap) {
        const int ky = tap / 9, kx = tap % 9;
        const size_t aoff = (size_t)(ky * 20 + kx) * 256;
        const size_t boff = (size_t)tap * 65536;
#pragma unroll
        for (int icc = 0; icc < 2; ++icc) {
            const int ic = ic_base + icc * 32;
            // stage: wave w owns k-chunk w (ic + w*8 .. +8)
#pragma unroll
            for (int q = 0; q < 2; ++q) {
                const unsigned short* ga  = h2hi + gArow[q] + aoff + ic + w * 8;
                const unsigned short* gal = h2lo + gArow[q] + aoff + ic + w * 8;
                const unsigned short* gb  = w4hi + boff + gBrow[q] + ic + w * 8;
                const unsigned short* gbl = w4lo + boff + gBrow[q] + ic + w * 8;
                GLD16(ga,  AsH + w * 1024 + q * 512);
                GLD16(gal, AsL + w * 1024 + q * 512);
                GLD16(gb,  BsH + w * 1024 + q * 512);
                GLD16(gbl, BsL + w * 1024 + q * 512);
            }
            __syncthreads();
            bf16x8 aH[4], aL[4], bH[4], bL[4];
#pragma unroll
            for (int i = 0; i < 4; ++i) {
                aH[i] = *(const bf16x8*)(AsH + ch + am + i * 128);
                aL[i] = *(const bf16x8*)(AsL + ch + am + i * 128);
                bH[i] = *(const bf16x8*)(BsH + ch + bn + i * 128);
                bL[i] = *(const bf16x8*)(BsL + ch + bn + i * 128);
            }
#pragma unroll
            for (int mi = 0; mi < 4; ++mi)
#pragma unroll
                for (int ni = 0; ni < 4; ++ni) {
                    f32x4 c = acc[mi][ni];
                    c = __builtin_amdgcn_mfma_f32_16x16x32_bf16(aH[mi], bH[ni], c, 0, 0, 0);
                    c = __builtin_amdgcn_mfma_f32_16x16x32_bf16(aH[mi], bL[ni], c, 0, 0, 0);
                    c = __builtin_amdgcn_mfma_f32_16x16x32_bf16(aL[mi], bH[ni], c, 0, 0, 0);
                    acc[mi][ni] = c;
                }
            __syncthreads();
        }
    }
    // epilogue: D[m][n], m=(lane>>4)*4+reg, n=lane&15
    const int row0 = (l >> 4) * 4;
    const int ncol = l & 15;
    float* base = pp + (size_t)ks * 9216 * 256;
#pragma unroll
    for (int mi = 0; mi < 4; ++mi)
#pragma unroll
        for (int ni = 0; ni < 4; ++ni) {
            int n = nt * 128 + wn * 64 + ni * 16 + ncol;
#pragma unroll
            for (int reg = 0; reg < 4; ++reg) {
                int m = mt * 128 + wm * 64 + mi * 16 + row0 + reg;
                base[(size_t)m * 256 + n] = acc[mi][ni][reg];
            }
        }
}

// ---------------- sum split-K partials + bias + primary squash -> u[b][i][d] ----------------
__global__ __launch_bounds__(256) void k_sum_squash2(const float* __restrict__ pp,
                                                     const float* __restrict__ bias,
                                                     float* __restrict__ u) {
    const size_t S = 9216UL * 256;
    int m = blockIdx.x * 8 + (threadIdx.x >> 5);
    int cap = threadIdx.x & 31;
    const float* p0 = pp + (size_t)m * 256 + cap * 8;
    float s[8], sq = 0.f;
#pragma unroll
    for (int d = 0; d < 8; ++d) {
        float a = p0[d] + p0[d + S] + p0[d + 2 * S] + p0[d + 3 * S] + bias[cap * 8 + d];
        sq += a * a; s[d] = a;
    }
    float scale = sq / ((1.0f + sq) * sqrtf(sq + 1e-8f));
    int b = m / 36, r = m % 36;
    float* up = u + ((size_t)b * NI + cap * 36 + r) * 8;
    ((float4*)up)[0] = make_float4(scale * s[0], scale * s[1], scale * s[2], scale * s[3]);
    ((float4*)up)[1] = make_float4(scale * s[4], scale * s[5], scale * s[6], scale * s[7]);
}

// ---------------- routing: s-partials (softmax fused, u_hat recomputed) ----------------
__global__ __launch_bounds__(256) void k_route_s(const float* __restrict__ L,
                                                 const float* __restrict__ U,
                                                 const float* __restrict__ W,
                                                 float* __restrict__ SP) {
    __shared__ float LG[64][81];
    __shared__ float UC[64][65];
    int it = blockIdx.x;  // 36
    int bt = blockIdx.y;  // 4
    int b0 = bt * 64;
    int b_l = threadIdx.x & 63;
    int og = __builtin_amdgcn_readfirstlane((int)(threadIdx.x >> 6));
    int b_r = threadIdx.x >> 2, part = threadIdx.x & 3;
    float acc[10][4];
#pragma unroll
    for (int j = 0; j < 10; ++j)
#pragma unroll
        for (int o = 0; o < 4; ++o) acc[j][o] = 0.f;

    for (int c8 = 0; c8 < 4; ++c8) {
        int i0 = it * 32 + c8 * 8;
        {
            const float4* lsrc = (const float4*)(L + (size_t)(b0 + b_r) * 11520 + i0 * 10 + part * 20);
#pragma unroll
            for (int q = 0; q < 5; ++q) {
                float4 t = lsrc[q]; int c = part * 20 + q * 4;
                LG[b_r][c] = t.x; LG[b_r][c + 1] = t.y; LG[b_r][c + 2] = t.z; LG[b_r][c + 3] = t.w;
            }
            const float4* usrc = (const float4*)(U + (size_t)(b0 + b_r) * 9216 + i0 * 8 + part * 16);
#pragma unroll
            for (int q = 0; q < 4; ++q) {
                float4 t = usrc[q]; int c = part * 16 + q * 4;
                UC[b_r][c] = t.x; UC[b_r][c + 1] = t.y; UC[b_r][c + 2] = t.z; UC[b_r][c + 3] = t.w;
            }
        }
        __syncthreads();
        for (int li = 0; li < 8; ++li) {
            float lg[10];
#pragma unroll
            for (int j = 0; j < 10; ++j) lg[j] = LG[b_l][li * 10 + j];
            float m = lg[0];
#pragma unroll
            for (int j = 1; j < 10; ++j) m = fmaxf(m, lg[j]);
            float e[10], ssum = 0.f;
#pragma unroll
            for (int j = 0; j < 10; ++j) { e[j] = __expf(lg[j] - m); ssum += e[j]; }
            float inv = 1.0f / ssum;
            float u8[8];
#pragma unroll
            for (int d = 0; d < 8; ++d) u8[d] = UC[b_l][li * 8 + d];
            const float* Wb = W + (size_t)(i0 + li) * 1280 + og * 4;
#pragma unroll
            for (int j = 0; j < 10; ++j) {
                float cj = e[j] * inv;
#pragma unroll
                for (int d = 0; d < 8; ++d) {
                    const float* wp = Wb + (d * 10 + j) * 16;
                    float f = cj * u8[d];
                    acc[j][0] += f * wp[0]; acc[j][1] += f * wp[1];
                    acc[j][2] += f * wp[2]; acc[j][3] += f * wp[3];
                }
            }
        }
        __syncthreads();
    }
    float* sp = SP + ((size_t)it * 256 + (b0 + b_l)) * 160 + og * 4;
#pragma unroll
    for (int j = 0; j < 10; ++j)
        *(float4*)(sp + j * 16) = make_float4(acc[j][0], acc[j][1], acc[j][2], acc[j][3]);
}

// ---------------- routing: reduce partials + squash -> v ----------------
__global__ __launch_bounds__(256) void k_route_v(const float* __restrict__ SP,
                                                 float* __restrict__ vout) {
    int n = blockIdx.x * 256 + threadIdx.x;  // 40960
    float ssum = 0.f;
#pragma unroll
    for (int t = 0; t < 36; ++t) ssum += SP[(size_t)t * 40960 + n];
    float sq = ssum * ssum;
    float tot = sq;
#pragma unroll
    for (int mask = 1; mask < 16; mask <<= 1) tot += __shfl_xor(tot, mask, 64);
    float scale = tot / ((1.0f + tot) * sqrtf(tot + 1e-8f));
    vout[n] = scale * ssum;
}

// ---------------- routing: agreement update b_logits += <u_hat, v> ----------------
__global__ __launch_bounds__(256) void k_route_agree(float* __restrict__ L,
                                                     const float* __restrict__ U,
                                                     const float* __restrict__ W,
                                                     const float* __restrict__ V) {
    __shared__ float LG[64][81];
    __shared__ float UC[64][65];
    __shared__ float VT[80][65];
    int it = blockIdx.x, bt = blockIdx.y;
    int b0 = bt * 64;
    int b_l = threadIdx.x & 63;
    int ig = __builtin_amdgcn_readfirstlane((int)(threadIdx.x >> 6));
    int b_r = threadIdx.x >> 2, part = threadIdx.x & 3;

    for (int jc = 0; jc < 2; ++jc) {
        __syncthreads();
        {
            const float4* vsrc = (const float4*)(V + (size_t)(b0 + b_r) * 160 + jc * 80 + part * 20);
#pragma unroll
            for (int q = 0; q < 5; ++q) {
                float4 vv = vsrc[q];
                int jo = part * 20 + q * 4;
                VT[jo][b_r] = vv.x; VT[jo + 1][b_r] = vv.y; VT[jo + 2][b_r] = vv.z; VT[jo + 3][b_r] = vv.w;
            }
        }
        for (int c8 = 0; c8 < 4; ++c8) {
            int i0 = it * 32 + c8 * 8;
            __syncthreads();
            {
                const float4* lsrc = (const float4*)(L + (size_t)(b0 + b_r) * 11520 + i0 * 10 + part * 20);
#pragma unroll
                for (int q = 0; q < 5; ++q) {
                    float4 t = lsrc[q]; int c = part * 20 + q * 4;
                    LG[b_r][c] = t.x; LG[b_r][c + 1] = t.y; LG[b_r][c + 2] = t.z; LG[b_r][c + 3] = t.w;
                }
                const float4* usrc = (const float4*)(U + (size_t)(b0 + b_r) * 9216 + i0 * 8 + part * 16);
#pragma unroll
                for (int q = 0; q < 4; ++q) {
                    float4 t = usrc[q]; int c = part * 16 + q * 4;
                    UC[b_r][c] = t.x; UC[b_r][c + 1] = t.y; UC[b_r][c + 2] = t.z; UC[b_r][c + 3] = t.w;
                }
            }
            __syncthreads();
            float u8a[8], u8b[8];
#pragma unroll
            for (int d = 0; d < 8; ++d) {
                u8a[d] = UC[b_l][(ig * 2) * 8 + d];
                u8b[d] = UC[b_l][(ig * 2 + 1) * 8 + d];
            }
            int ia = i0 + ig * 2, ib2 = ia + 1;
#pragma unroll
            for (int jj = 0; jj < 5; ++jj) {
                int j = jc * 5 + jj;
                float v16[16];
#pragma unroll
                for (int o = 0; o < 16; ++o) v16[o] = VT[jj * 16 + o][b_l];
                const float* W0 = W + (size_t)ia * 1280 + j * 16;
                const float* W1 = W + (size_t)ib2 * 1280 + j * 16;
                float a0 = 0.f, a1 = 0.f;
#pragma unroll
                for (int d = 0; d < 8; ++d) {
                    float wv0 = 0.f, wv1 = 0.f;
#pragma unroll
                    for (int o = 0; o < 16; ++o) {
                        wv0 += W0[d * 160 + o] * v16[o];
                        wv1 += W1[d * 160 + o] * v16[o];
                    }
                    a0 += u8a[d] * wv0; a1 += u8b[d] * wv1;
                }
                LG[b_l][(ig * 2) * 10 + j] += a0;
                LG[b_l][(ig * 2 + 1) * 10 + j] += a1;
            }
            __syncthreads();
            {
                float4* ldst = (float4*)(L + (size_t)(b0 + b_r) * 11520 + i0 * 10 + part * 20);
#pragma unroll
                for (int q = 0; q < 5; ++q) {
                    int c = part * 20 + q * 4;
                    ldst[q] = make_float4(LG[b_r][c], LG[b_r][c + 1], LG[b_r][c + 2], LG[b_r][c + 3]);
                }
            }
        }
    }
}

// ---------------- launcher ----------------
extern "C" void kernel_launch(void* const* d_in, const int* in_sizes, int n_in,
                              void* d_out, int out_size, void* d_ws, size_t ws_size,
                              hipStream_t stream) {
    (void)in_sizes; (void)n_in; (void)out_size; (void)ws_size;
    const float* x   = (const float*)d_in[0];
    const float* c1w = (const float*)d_in[1];
    const float* c1b = (const float*)d_in[2];
    const float* pcw = (const float*)d_in[3];
    const float* pcb = (const float*)d_in[4];
    const float* Wd  = (const float*)d_in[5];
    float* out = (float*)d_out;
    char* wsb  = (char*)d_ws;

    unsigned short* w4hi = (unsigned short*)(wsb + W4HI_OFF);
    unsigned short* w4lo = (unsigned short*)(wsb + W4LO_OFF);
    unsigned short* h2hi = (unsigned short*)(wsb + H2HI_OFF);
    unsigned short* h2lo = (unsigned short*)(wsb + H2LO_OFF);
    float* wT1 = (float*)(wsb + WT1_OFF);
    float* pp  = (float*)(wsb + PP_OFF);
    float* u   = (float*)(wsb + U_OFF);
    float* lg  = (float*)(wsb + LG_OFF);
    float* sp  = (float*)(wsb + SP_OFF);
    float* v   = (float*)(wsb + V_OFF);

    hipMemsetAsync(lg, 0, (size_t)256 * 1152 * 10 * sizeof(float), stream);

    k_prep_w<<<dim3(256, 4), 256, 0, stream>>>(pcw, w4hi, w4lo);
    k_transpose_w1<<<81, 256, 0, stream>>>(c1w, wT1);
    k_conv1<<<dim3(10, 256), 256, 0, stream>>>(x, wT1, c1b, h2hi, h2lo);
    k_conv2_mfma<<<dim3(72, 2, 4), 256, 0, stream>>>(h2hi, h2lo, w4hi, w4lo, pp);
    k_sum_squash2<<<1152, 256, 0, stream>>>(pp, pcb, u);

    for (int itr = 0; itr < 3; ++itr) {
        k_route_s<<<dim3(36, 4), 256, 0, stream>>>(lg, u, Wd, sp);
        k_route_v<<<160, 256, 0, stream>>>(sp, (itr == 2) ? out : v);
        if (itr < 2)
            k_route_agree<<<dim3(36, 4), 256, 0, stream>>>(lg, u, Wd, v);
    }
}

// Round 3
// 1424.778 us; speedup vs baseline: 2.0484x; 1.0205x over previous
//
#include <hip/hip_runtime.h>
#include <hip/hip_bf16.h>

// ---------------- problem constants ----------------
#define NI   1152
// GEMM view of primary-caps conv: M=9216 (b,py,px), N=256 (oc), K=81 taps x 256 ic

typedef __attribute__((ext_vector_type(8))) short bf16x8;
typedef __attribute__((ext_vector_type(4))) float f32x4;

// ws layout (bytes)
static const size_t W4HI_OFF = 0;                         // 81*256*256 bf16
static const size_t W4LO_OFF = W4HI_OFF + 10616832UL;
static const size_t H2HI_OFF = W4LO_OFF + 10616832UL;     // 256*20*20*256 bf16
static const size_t H2LO_OFF = H2HI_OFF + 52428800UL;
static const size_t WT1_OFF  = H2LO_OFF + 52428800UL;     // 81*256 f32
static const size_t PP_OFF   = WT1_OFF + 82944UL;         // 4*9216*256 f32 (37.7MB)
static const size_t SP_OFF   = PP_OFF;                    // aliased: 144*256*160 f32 (23.6MB), used after pp dead
static const size_t U_OFF    = PP_OFF + 37748736UL;       // 256*1152*8 f32
static const size_t LG_OFF   = U_OFF + 9437184UL;         // 256*1152*10 f32
static const size_t V_OFF    = LG_OFF + 11796480UL;       // 256*160 f32

__device__ __forceinline__ unsigned short f2bf(float x) {
    unsigned u = __builtin_bit_cast(unsigned, x);
    u += 0x7fffu + ((u >> 16) & 1u);
    return (unsigned short)(u >> 16);
}
__device__ __forceinline__ float bf2f(unsigned short h) {
    return __builtin_bit_cast(float, (unsigned)h << 16);
}

// ---------------- weight prep: pc_w [oc][ic*81+tap] -> w4{hi,lo}[tap][oc][ic] ----------------
__global__ __launch_bounds__(256) void k_prep_w(const float* __restrict__ pcw,
                                                unsigned short* __restrict__ w4hi,
                                                unsigned short* __restrict__ w4lo) {
    __shared__ float sl[5184];
    int oc  = blockIdx.x;       // 256
    int ic0 = blockIdx.y * 64;  // 4 chunks
    const float* src = pcw + (size_t)oc * 20736 + (size_t)ic0 * 81;
    for (int j = threadIdx.x; j < 5184; j += 256) sl[j] = src[j];
    __syncthreads();
    for (int t = threadIdx.x; t < 5184; t += 256) {
        int tap = t >> 6, i = t & 63;
        float x = sl[i * 81 + tap];
        unsigned short hi = f2bf(x);
        size_t idx = (size_t)tap * 65536 + (size_t)oc * 256 + ic0 + i;
        w4hi[idx] = hi;
        w4lo[idx] = f2bf(x - bf2f(hi));
    }
}

// conv1_w [oc][81] -> wT1 [t][oc]
__global__ void k_transpose_w1(const float* __restrict__ w, float* __restrict__ wT) {
    int t = blockIdx.x, oc = threadIdx.x;
    wT[t * 256 + oc] = w[oc * 81 + t];
}

// ---------------- conv1 + relu -> h2{hi,lo}[b][y][x][oc] bf16 split ----------------
__global__ __launch_bounds__(256) void k_conv1(const float* __restrict__ x,
                                               const float* __restrict__ wT1,
                                               const float* __restrict__ bias,
                                               unsigned short* __restrict__ h2hi,
                                               unsigned short* __restrict__ h2lo) {
    int b  = blockIdx.y;    // 256
    int rp = blockIdx.x;    // 10 row-pairs
    int oc = threadIdx.x;   // 256
    int oy0 = rp * 2;
    const float* xb = x + (size_t)b * 784;
    float bv = bias[oc];
    float acc0[20], acc1[20];
#pragma unroll
    for (int i = 0; i < 20; ++i) { acc0[i] = bv; acc1[i] = bv; }
    for (int ky = 0; ky < 9; ++ky) {
        const float* r0 = xb + (oy0 + ky) * 28;
        const float* r1 = r0 + 28;
        float x0[28], x1[28];
#pragma unroll
        for (int c = 0; c < 28; ++c) { x0[c] = r0[c]; x1[c] = r1[c]; }
#pragma unroll
        for (int kx = 0; kx < 9; ++kx) {
            float w = wT1[(ky * 9 + kx) * 256 + oc];
#pragma unroll
            for (int px = 0; px < 20; ++px) {
                acc0[px] += x0[px + kx] * w;
                acc1[px] += x1[px + kx] * w;
            }
        }
    }
#pragma unroll
    for (int px = 0; px < 20; ++px) {
        float v0 = fmaxf(acc0[px], 0.f), v1 = fmaxf(acc1[px], 0.f);
        size_t i0 = (size_t)((b * 20 + oy0) * 20 + px) * 256 + oc;
        size_t i1 = (size_t)((b * 20 + oy0 + 1) * 20 + px) * 256 + oc;
        unsigned short h0 = f2bf(v0), h1 = f2bf(v1);
        h2hi[i0] = h0; h2lo[i0] = f2bf(v0 - bf2f(h0));
        h2hi[i1] = h1; h2lo[i1] = f2bf(v1 - bf2f(h1));
    }
}

// ---------------- primary caps conv: LDS-free direct-fragment MFMA ----------------
// grid (72 mt, 2 nt, 4 ks); block 256 = 4 waves (2x2), wave tile 64x64.
// Fragments loaded straight from global (channels-last => 16B contiguous per lane).
// No __syncthreads / LDS in the K-loop: waves pipeline independently.
__global__ __launch_bounds__(256, 3) void k_conv2_direct(
    const unsigned short* __restrict__ h2hi, const unsigned short* __restrict__ h2lo,
    const unsigned short* __restrict__ w4hi, const unsigned short* __restrict__ w4lo,
    float* __restrict__ pp) {
    const int mt = blockIdx.x, nt = blockIdx.y, ks = blockIdx.z;
    const int l = threadIdx.x & 63;
    const int w = threadIdx.x >> 6;
    const int wm = w >> 1, wn = w & 1;
    const int kch = (l >> 4) * 8;   // k-chunk element offset within 32
    const int r16 = l & 15;
    const int ic0 = ks * 64;

    int abase[4], bbase[4];
#pragma unroll
    for (int mi = 0; mi < 4; ++mi) {
        int m = mt * 128 + wm * 64 + mi * 16 + r16;
        int b = m / 36, r = m % 36;
        int py = r / 6, px = r % 6;
        abase[mi] = ((b * 20 + 2 * py) * 20 + 2 * px) * 256 + ic0 + kch;
    }
#pragma unroll
    for (int ni = 0; ni < 4; ++ni)
        bbase[ni] = (nt * 128 + wn * 64 + ni * 16 + r16) * 256 + ic0 + kch;

    f32x4 acc[4][4];
    const f32x4 z = {0.f, 0.f, 0.f, 0.f};
#pragma unroll
    for (int mi = 0; mi < 4; ++mi)
#pragma unroll
        for (int ni = 0; ni < 4; ++ni) acc[mi][ni] = z;

    int tap = 0;
    for (int ky = 0; ky < 9; ++ky) {
#pragma unroll
        for (int kx = 0; kx < 9; ++kx, ++tap) {
            const int aoff = (ky * 20 + kx) * 256;
            const int boff = tap * 65536;
#pragma unroll
            for (int icc = 0; icc < 2; ++icc) {
                const int ico = icc * 32;
                bf16x8 aH[4], aL[4], bH[4], bL[4];
#pragma unroll
                for (int i = 0; i < 4; ++i) {
                    aH[i] = *(const bf16x8*)(h2hi + abase[i] + aoff + ico);
                    aL[i] = *(const bf16x8*)(h2lo + abase[i] + aoff + ico);
                    bH[i] = *(const bf16x8*)(w4hi + boff + bbase[i] + ico);
                    bL[i] = *(const bf16x8*)(w4lo + boff + bbase[i] + ico);
                }
#pragma unroll
                for (int mi = 0; mi < 4; ++mi)
#pragma unroll
                    for (int ni = 0; ni < 4; ++ni) {
                        f32x4 c = acc[mi][ni];
                        c = __builtin_amdgcn_mfma_f32_16x16x32_bf16(aH[mi], bH[ni], c, 0, 0, 0);
                        c = __builtin_amdgcn_mfma_f32_16x16x32_bf16(aH[mi], bL[ni], c, 0, 0, 0);
                        c = __builtin_amdgcn_mfma_f32_16x16x32_bf16(aL[mi], bH[ni], c, 0, 0, 0);
                        acc[mi][ni] = c;
                    }
            }
        }
    }
    // epilogue: D[m][n], m=(lane>>4)*4+reg, n=lane&15 (verified R2)
    const int row0 = (l >> 4) * 4;
    const int ncol = l & 15;
    float* base = pp + (size_t)ks * 9216 * 256;
#pragma unroll
    for (int mi = 0; mi < 4; ++mi)
#pragma unroll
        for (int ni = 0; ni < 4; ++ni) {
            int n = nt * 128 + wn * 64 + ni * 16 + ncol;
#pragma unroll
            for (int reg = 0; reg < 4; ++reg) {
                int m = mt * 128 + wm * 64 + mi * 16 + row0 + reg;
                base[(size_t)m * 256 + n] = acc[mi][ni][reg];
            }
        }
}

// ---------------- sum split-K partials + bias + primary squash -> u[b][i][d] ----------------
__global__ __launch_bounds__(256) void k_sum_squash2(const float* __restrict__ pp,
                                                     const float* __restrict__ bias,
                                                     float* __restrict__ u) {
    const size_t S = 9216UL * 256;
    int m = blockIdx.x * 8 + (threadIdx.x >> 5);
    int cap = threadIdx.x & 31;
    const float* p0 = pp + (size_t)m * 256 + cap * 8;
    float s[8], sq = 0.f;
#pragma unroll
    for (int d = 0; d < 8; ++d) {
        float a = p0[d] + p0[d + S] + p0[d + 2 * S] + p0[d + 3 * S] + bias[cap * 8 + d];
        sq += a * a; s[d] = a;
    }
    float scale = sq / ((1.0f + sq) * sqrtf(sq + 1e-8f));
    int b = m / 36, r = m % 36;
    float* up = u + ((size_t)b * NI + cap * 36 + r) * 8;
    ((float4*)up)[0] = make_float4(scale * s[0], scale * s[1], scale * s[2], scale * s[3]);
    ((float4*)up)[1] = make_float4(scale * s[4], scale * s[5], scale * s[6], scale * s[7]);
}

// ---------------- routing: s-partials (softmax fused, u_hat recomputed) ----------------
// grid (144 i-tiles of 8, 4 b-tiles); block 256 = 64 b_lanes x 4 o-groups
__global__ __launch_bounds__(256) void k_route_s(const float* __restrict__ L,
                                                 const float* __restrict__ U,
                                                 const float* __restrict__ W,
                                                 float* __restrict__ SP) {
    __shared__ float LG[64][81];
    __shared__ float UC[64][65];
    int it = blockIdx.x;  // 144
    int bt = blockIdx.y;  // 4
    int b0 = bt * 64;
    int b_l = threadIdx.x & 63;
    int og = __builtin_amdgcn_readfirstlane((int)(threadIdx.x >> 6));
    int b_r = threadIdx.x >> 2, part = threadIdx.x & 3;
    int i0 = it * 8;
    float acc[10][4];
#pragma unroll
    for (int j = 0; j < 10; ++j)
#pragma unroll
        for (int o = 0; o < 4; ++o) acc[j][o] = 0.f;

    {
        const float4* lsrc = (const float4*)(L + (size_t)(b0 + b_r) * 11520 + i0 * 10 + part * 20);
#pragma unroll
        for (int q = 0; q < 5; ++q) {
            float4 t = lsrc[q]; int c = part * 20 + q * 4;
            LG[b_r][c] = t.x; LG[b_r][c + 1] = t.y; LG[b_r][c + 2] = t.z; LG[b_r][c + 3] = t.w;
        }
        const float4* usrc = (const float4*)(U + (size_t)(b0 + b_r) * 9216 + i0 * 8 + part * 16);
#pragma unroll
        for (int q = 0; q < 4; ++q) {
            float4 t = usrc[q]; int c = part * 16 + q * 4;
            UC[b_r][c] = t.x; UC[b_r][c + 1] = t.y; UC[b_r][c + 2] = t.z; UC[b_r][c + 3] = t.w;
        }
    }
    __syncthreads();
    for (int li = 0; li < 8; ++li) {
        float lg[10];
#pragma unroll
        for (int j = 0; j < 10; ++j) lg[j] = LG[b_l][li * 10 + j];
        float m = lg[0];
#pragma unroll
        for (int j = 1; j < 10; ++j) m = fmaxf(m, lg[j]);
        float e[10], ssum = 0.f;
#pragma unroll
        for (int j = 0; j < 10; ++j) { e[j] = __expf(lg[j] - m); ssum += e[j]; }
        float inv = 1.0f / ssum;
        float u8[8];
#pragma unroll
        for (int d = 0; d < 8; ++d) u8[d] = UC[b_l][li * 8 + d];
        const float* Wb = W + (size_t)(i0 + li) * 1280 + og * 4;
#pragma unroll
        for (int j = 0; j < 10; ++j) {
            float cj = e[j] * inv;
#pragma unroll
            for (int d = 0; d < 8; ++d) {
                const float* wp = Wb + (d * 10 + j) * 16;
                float f = cj * u8[d];
                acc[j][0] += f * wp[0]; acc[j][1] += f * wp[1];
                acc[j][2] += f * wp[2]; acc[j][3] += f * wp[3];
            }
        }
    }
    float* sp = SP + ((size_t)it * 256 + (b0 + b_l)) * 160 + og * 4;
#pragma unroll
    for (int j = 0; j < 10; ++j)
        *(float4*)(sp + j * 16) = make_float4(acc[j][0], acc[j][1], acc[j][2], acc[j][3]);
}

// ---------------- routing: reduce partials + squash -> v ----------------
__global__ __launch_bounds__(256) void k_route_v(const float* __restrict__ SP,
                                                 float* __restrict__ vout) {
    int n = blockIdx.x * 256 + threadIdx.x;  // 40960
    float ssum = 0.f;
    for (int t = 0; t < 144; ++t) ssum += SP[(size_t)t * 40960 + n];
    float sq = ssum * ssum;
    float tot = sq;
#pragma unroll
    for (int mask = 1; mask < 16; mask <<= 1) tot += __shfl_xor(tot, mask, 64);
    float scale = tot / ((1.0f + tot) * sqrtf(tot + 1e-8f));
    vout[n] = scale * ssum;
}

// ---------------- routing: agreement update b_logits += <u_hat, v> ----------------
// grid (144 i-tiles of 8, 4 b-tiles); block 256 = 64 b_lanes x 4 i-groups (2 i each)
__global__ __launch_bounds__(256) void k_route_agree(float* __restrict__ L,
                                                     const float* __restrict__ U,
                                                     const float* __restrict__ W,
                                                     const float* __restrict__ V) {
    __shared__ float LG[64][81];
    __shared__ float UC[64][65];
    __shared__ float VT[160][65];
    int it = blockIdx.x, bt = blockIdx.y;
    int b0 = bt * 64;
    int b_l = threadIdx.x & 63;
    int ig = __builtin_amdgcn_readfirstlane((int)(threadIdx.x >> 6));
    int b_r = threadIdx.x >> 2, part = threadIdx.x & 3;
    int i0 = it * 8;

    {   // stage v (all 160 jo), transposed
        const float4* vsrc = (const float4*)(V + (size_t)(b0 + b_r) * 160 + part * 40);
#pragma unroll
        for (int q = 0; q < 10; ++q) {
            float4 vv = vsrc[q];
            int jo = part * 40 + q * 4;
            VT[jo][b_r] = vv.x; VT[jo + 1][b_r] = vv.y; VT[jo + 2][b_r] = vv.z; VT[jo + 3][b_r] = vv.w;
        }
        const float4* lsrc = (const float4*)(L + (size_t)(b0 + b_r) * 11520 + i0 * 10 + part * 20);
#pragma unroll
        for (int q = 0; q < 5; ++q) {
            float4 t = lsrc[q]; int c = part * 20 + q * 4;
            LG[b_r][c] = t.x; LG[b_r][c + 1] = t.y; LG[b_r][c + 2] = t.z; LG[b_r][c + 3] = t.w;
        }
        const float4* usrc = (const float4*)(U + (size_t)(b0 + b_r) * 9216 + i0 * 8 + part * 16);
#pragma unroll
        for (int q = 0; q < 4; ++q) {
            float4 t = usrc[q]; int c = part * 16 + q * 4;
            UC[b_r][c] = t.x; UC[b_r][c + 1] = t.y; UC[b_r][c + 2] = t.z; UC[b_r][c + 3] = t.w;
        }
    }
    __syncthreads();
#pragma unroll
    for (int ii = 0; ii < 2; ++ii) {
        int ilocal = ig * 2 + ii;
        int i = i0 + ilocal;
        float u8[8];
#pragma unroll
        for (int d = 0; d < 8; ++d) u8[d] = UC[b_l][ilocal * 8 + d];
        const float* Wi = W + (size_t)i * 1280;
#pragma unroll
        for (int j = 0; j < 10; ++j) {
            float v16[16];
#pragma unroll
            for (int o = 0; o < 16; ++o) v16[o] = VT[j * 16 + o][b_l];
            float a = 0.f;
#pragma unroll
            for (int d = 0; d < 8; ++d) {
                const float* wp = Wi + d * 160 + j * 16;
                float wv = 0.f;
#pragma unroll
                for (int o = 0; o < 16; ++o) wv += wp[o] * v16[o];
                a += u8[d] * wv;
            }
            LG[b_l][ilocal * 10 + j] += a;
        }
    }
    __syncthreads();
    {
        float4* ldst = (float4*)(L + (size_t)(b0 + b_r) * 11520 + i0 * 10 + part * 20);
#pragma unroll
        for (int q = 0; q < 5; ++q) {
            int c = part * 20 + q * 4;
            ldst[q] = make_float4(LG[b_r][c], LG[b_r][c + 1], LG[b_r][c + 2], LG[b_r][c + 3]);
        }
    }
}

// ---------------- launcher ----------------
extern "C" void kernel_launch(void* const* d_in, const int* in_sizes, int n_in,
                              void* d_out, int out_size, void* d_ws, size_t ws_size,
                              hipStream_t stream) {
    (void)in_sizes; (void)n_in; (void)out_size; (void)ws_size;
    const float* x   = (const float*)d_in[0];
    const float* c1w = (const float*)d_in[1];
    const float* c1b = (const float*)d_in[2];
    const float* pcw = (const float*)d_in[3];
    const float* pcb = (const float*)d_in[4];
    const float* Wd  = (const float*)d_in[5];
    float* out = (float*)d_out;
    char* wsb  = (char*)d_ws;

    unsigned short* w4hi = (unsigned short*)(wsb + W4HI_OFF);
    unsigned short* w4lo = (unsigned short*)(wsb + W4LO_OFF);
    unsigned short* h2hi = (unsigned short*)(wsb + H2HI_OFF);
    unsigned short* h2lo = (unsigned short*)(wsb + H2LO_OFF);
    float* wT1 = (float*)(wsb + WT1_OFF);
    float* pp  = (float*)(wsb + PP_OFF);
    float* sp  = (float*)(wsb + SP_OFF);  // aliases pp (pp dead after k_sum_squash2)
    float* u   = (float*)(wsb + U_OFF);
    float* lg  = (float*)(wsb + LG_OFF);
    float* v   = (float*)(wsb + V_OFF);

    hipMemsetAsync(lg, 0, (size_t)256 * 1152 * 10 * sizeof(float), stream);

    k_prep_w<<<dim3(256, 4), 256, 0, stream>>>(pcw, w4hi, w4lo);
    k_transpose_w1<<<81, 256, 0, stream>>>(c1w, wT1);
    k_conv1<<<dim3(10, 256), 256, 0, stream>>>(x, wT1, c1b, h2hi, h2lo);
    k_conv2_direct<<<dim3(72, 2, 4), 256, 0, stream>>>(h2hi, h2lo, w4hi, w4lo, pp);
    k_sum_squash2<<<1152, 256, 0, stream>>>(pp, pcb, u);

    for (int itr = 0; itr < 3; ++itr) {
        k_route_s<<<dim3(144, 4), 256, 0, stream>>>(lg, u, Wd, sp);
        k_route_v<<<160, 256, 0, stream>>>(sp, (itr == 2) ? out : v);
        if (itr < 2)
            k_route_agree<<<dim3(144, 4), 256, 0, stream>>>(lg, u, Wd, v);
    }
}

// Round 4
// 1026.546 us; speedup vs baseline: 2.8430x; 1.3879x over previous
//
#include <hip/hip_runtime.h>
#include <hip/hip_bf16.h>

// ---------------- problem constants ----------------
#define NI   1152
// GEMM view of primary-caps conv: M=9216 (b,py,px), N=256 (oc), K=81 taps x 256 ic

typedef __attribute__((ext_vector_type(8))) short bf16x8;
typedef __attribute__((ext_vector_type(4))) float f32x4;

// ws layout (bytes)
static const size_t W4HI_OFF = 0;                         // 81*256*256 bf16
static const size_t W4LO_OFF = W4HI_OFF + 10616832UL;
static const size_t H2HI_OFF = W4LO_OFF + 10616832UL;     // 256*20*20*256 bf16 (52.4MB)
static const size_t SP_OFF   = H2HI_OFF;                  // aliased: 144*256*160 f32 (23.6MB), after h2 dead
static const size_t H2LO_OFF = H2HI_OFF + 52428800UL;
static const size_t WT1_OFF  = H2LO_OFF + 52428800UL;     // 81*256 f32
static const size_t PP_OFF   = WT1_OFF + 82944UL;         // 9216*256 f32 (9.4MB, atomic-accumulated)
static const size_t U_OFF    = PP_OFF + 9437184UL;        // 256*1152*8 f32
static const size_t LG_OFF   = U_OFF + 9437184UL;         // 256*1152*10 f32
static const size_t V_OFF    = LG_OFF + 11796480UL;       // 256*160 f32

__device__ __forceinline__ unsigned short f2bf(float x) {
    unsigned u = __builtin_bit_cast(unsigned, x);
    u += 0x7fffu + ((u >> 16) & 1u);
    return (unsigned short)(u >> 16);
}
__device__ __forceinline__ float bf2f(unsigned short h) {
    return __builtin_bit_cast(float, (unsigned)h << 16);
}
__device__ __forceinline__ void atomAddF(float* p, float v) {
    __hip_atomic_fetch_add(p, v, __ATOMIC_RELAXED, __HIP_MEMORY_SCOPE_AGENT);
}

#define GLD16(gsrc, ldst)                                                      \
    __builtin_amdgcn_global_load_lds(                                          \
        (__attribute__((address_space(1))) const void*)(gsrc),                 \
        (__attribute__((address_space(3))) void*)(ldst), 16, 0, 0)

// ---------------- weight prep: pc_w [oc][ic*81+tap] -> w4{hi,lo}[tap][oc][ic] ----------------
__global__ __launch_bounds__(256) void k_prep_w(const float* __restrict__ pcw,
                                                unsigned short* __restrict__ w4hi,
                                                unsigned short* __restrict__ w4lo) {
    __shared__ float sl[5184];
    int oc  = blockIdx.x;       // 256
    int ic0 = blockIdx.y * 64;  // 4 chunks
    const float* src = pcw + (size_t)oc * 20736 + (size_t)ic0 * 81;
    for (int j = threadIdx.x; j < 5184; j += 256) sl[j] = src[j];
    __syncthreads();
    for (int t = threadIdx.x; t < 5184; t += 256) {
        int tap = t >> 6, i = t & 63;
        float x = sl[i * 81 + tap];
        unsigned short hi = f2bf(x);
        size_t idx = (size_t)tap * 65536 + (size_t)oc * 256 + ic0 + i;
        w4hi[idx] = hi;
        w4lo[idx] = f2bf(x - bf2f(hi));
    }
}

// conv1_w [oc][81] -> wT1 [t][oc]
__global__ void k_transpose_w1(const float* __restrict__ w, float* __restrict__ wT) {
    int t = blockIdx.x, oc = threadIdx.x;
    wT[t * 256 + oc] = w[oc * 81 + t];
}

// ---------------- conv1 + relu -> h2{hi,lo}[b][y][x][oc] bf16 split ----------------
__global__ __launch_bounds__(256) void k_conv1(const float* __restrict__ x,
                                               const float* __restrict__ wT1,
                                               const float* __restrict__ bias,
                                               unsigned short* __restrict__ h2hi,
                                               unsigned short* __restrict__ h2lo) {
    int b  = blockIdx.y;    // 256
    int rp = blockIdx.x;    // 10 row-pairs
    int oc = threadIdx.x;   // 256
    int oy0 = rp * 2;
    const float* xb = x + (size_t)b * 784;
    float bv = bias[oc];
    float acc0[20], acc1[20];
#pragma unroll
    for (int i = 0; i < 20; ++i) { acc0[i] = bv; acc1[i] = bv; }
    for (int ky = 0; ky < 9; ++ky) {
        const float* r0 = xb + (oy0 + ky) * 28;
        const float* r1 = r0 + 28;
        float x0[28], x1[28];
#pragma unroll
        for (int c = 0; c < 28; ++c) { x0[c] = r0[c]; x1[c] = r1[c]; }
#pragma unroll
        for (int kx = 0; kx < 9; ++kx) {
            float w = wT1[(ky * 9 + kx) * 256 + oc];
#pragma unroll
            for (int px = 0; px < 20; ++px) {
                acc0[px] += x0[px + kx] * w;
                acc1[px] += x1[px + kx] * w;
            }
        }
    }
#pragma unroll
    for (int px = 0; px < 20; ++px) {
        float v0 = fmaxf(acc0[px], 0.f), v1 = fmaxf(acc1[px], 0.f);
        size_t i0 = (size_t)((b * 20 + oy0) * 20 + px) * 256 + oc;
        size_t i1 = (size_t)((b * 20 + oy0 + 1) * 20 + px) * 256 + oc;
        unsigned short h0 = f2bf(v0), h1 = f2bf(v1);
        h2hi[i0] = h0; h2lo[i0] = f2bf(v0 - bf2f(h0));
        h2hi[i1] = h1; h2lo[i1] = f2bf(v1 - bf2f(h1));
    }
}

// ---------------- primary caps conv as MFMA implicit GEMM (split-bf16, 3 passes) ----------------
// grid (72 mt, 2 nt, 8 ks); block 256 = 4 waves; 128x128 tile, BK=32 (one tap-slab per barrier pair).
// LDS per operand: 4 k-chunk planes x 128 rows x 8 bf16 (measured conflict-free in R2).
// Epilogue: native fp32 atomic add into a single pp plane (8 k-splits accumulate).
__global__ __launch_bounds__(256, 3) void k_conv2_mfma(
    const unsigned short* __restrict__ h2hi, const unsigned short* __restrict__ h2lo,
    const unsigned short* __restrict__ w4hi, const unsigned short* __restrict__ w4lo,
    float* __restrict__ pp) {
    __shared__ unsigned short AsH[4096], AsL[4096], BsH[4096], BsL[4096];
    const int mt = blockIdx.x, nt = blockIdx.y, ks = blockIdx.z;
    const int l = threadIdx.x & 63;
    const int w = __builtin_amdgcn_readfirstlane((int)(threadIdx.x >> 6));
    const int wm = w >> 1, wn = w & 1;

    // per-lane staging source rows (element offsets); lane l stages row q*64+l
    size_t gArow[2], gBrow[2];
#pragma unroll
    for (int q = 0; q < 2; ++q) {
        int m = mt * 128 + q * 64 + l;
        int b = m / 36, r = m % 36;
        int py = r / 6, px = r % 6;
        gArow[q] = ((size_t)(b * 20 + 2 * py) * 20 + 2 * px) * 256;
        gBrow[q] = (size_t)(nt * 128 + q * 64 + l) * 256;
    }
    const int icw = ks * 32 + w * 8;  // this wave's staged k-chunk

    f32x4 acc[4][4];
    const f32x4 z = {0.f, 0.f, 0.f, 0.f};
#pragma unroll
    for (int mi = 0; mi < 4; ++mi)
#pragma unroll
        for (int ni = 0; ni < 4; ++ni) acc[mi][ni] = z;

    const int ch = (l >> 4) * 1024;           // k-chunk plane (ushorts)
    const int am = (wm * 64 + (l & 15)) * 8;  // a-frag row offset within plane
    const int bn = (wn * 64 + (l & 15)) * 8;  // b-frag row offset within plane

    int tap = 0;
    for (int ky = 0; ky < 9; ++ky) {
        for (int kx = 0; kx < 9; ++kx, ++tap) {
            const size_t aoff = (size_t)(ky * 20 + kx) * 256 + icw;
            const size_t boff = (size_t)tap * 65536 + icw;
#pragma unroll
            for (int q = 0; q < 2; ++q) {
                GLD16(h2hi + gArow[q] + aoff, AsH + w * 1024 + q * 512);
                GLD16(h2lo + gArow[q] + aoff, AsL + w * 1024 + q * 512);
                GLD16(w4hi + boff + gBrow[q], BsH + w * 1024 + q * 512);
                GLD16(w4lo + boff + gBrow[q], BsL + w * 1024 + q * 512);
            }
            __syncthreads();
            bf16x8 aH[4], aL[4], bH[4], bL[4];
#pragma unroll
            for (int i = 0; i < 4; ++i) {
                aH[i] = *(const bf16x8*)(AsH + ch + am + i * 128);
                aL[i] = *(const bf16x8*)(AsL + ch + am + i * 128);
                bH[i] = *(const bf16x8*)(BsH + ch + bn + i * 128);
                bL[i] = *(const bf16x8*)(BsL + ch + bn + i * 128);
            }
#pragma unroll
            for (int mi = 0; mi < 4; ++mi)
#pragma unroll
                for (int ni = 0; ni < 4; ++ni) {
                    f32x4 c = acc[mi][ni];
                    c = __builtin_amdgcn_mfma_f32_16x16x32_bf16(aH[mi], bH[ni], c, 0, 0, 0);
                    c = __builtin_amdgcn_mfma_f32_16x16x32_bf16(aH[mi], bL[ni], c, 0, 0, 0);
                    c = __builtin_amdgcn_mfma_f32_16x16x32_bf16(aL[mi], bH[ni], c, 0, 0, 0);
                    acc[mi][ni] = c;
                }
            __syncthreads();
        }
    }
    // epilogue: D[m][n], m=(lane>>4)*4+reg, n=lane&15 (verified R2); atomic split-K reduce
    const int row0 = (l >> 4) * 4;
    const int ncol = l & 15;
#pragma unroll
    for (int mi = 0; mi < 4; ++mi)
#pragma unroll
        for (int ni = 0; ni < 4; ++ni) {
            int n = nt * 128 + wn * 64 + ni * 16 + ncol;
#pragma unroll
            for (int reg = 0; reg < 4; ++reg) {
                int m = mt * 128 + wm * 64 + mi * 16 + row0 + reg;
                atomAddF(&pp[(size_t)m * 256 + n], acc[mi][ni][reg]);
            }
        }
}

// ---------------- bias + primary squash -> u[b][i][d] ----------------
__global__ __launch_bounds__(256) void k_sum_squash2(const float* __restrict__ pp,
                                                     const float* __restrict__ bias,
                                                     float* __restrict__ u) {
    int m = blockIdx.x * 8 + (threadIdx.x >> 5);
    int cap = threadIdx.x & 31;
    const float* p0 = pp + (size_t)m * 256 + cap * 8;
    float s[8], sq = 0.f;
#pragma unroll
    for (int d = 0; d < 8; ++d) {
        float a = p0[d] + bias[cap * 8 + d];
        sq += a * a; s[d] = a;
    }
    float scale = sq / ((1.0f + sq) * sqrtf(sq + 1e-8f));
    int b = m / 36, r = m % 36;
    float* up = u + ((size_t)b * NI + cap * 36 + r) * 8;
    ((float4*)up)[0] = make_float4(scale * s[0], scale * s[1], scale * s[2], scale * s[3]);
    ((float4*)up)[1] = make_float4(scale * s[4], scale * s[5], scale * s[6], scale * s[7]);
}

// ---------------- routing: s-partials (softmax fused, u_hat recomputed) ----------------
// grid (144 i-tiles of 8, 4 b-tiles); block 256 = 64 b_lanes x 4 o-groups
__global__ __launch_bounds__(256) void k_route_s(const float* __restrict__ L,
                                                 const float* __restrict__ U,
                                                 const float* __restrict__ W,
                                                 float* __restrict__ SP) {
    __shared__ float LG[64][81];
    __shared__ float UC[64][65];
    int it = blockIdx.x;  // 144
    int bt = blockIdx.y;  // 4
    int b0 = bt * 64;
    int b_l = threadIdx.x & 63;
    int og = __builtin_amdgcn_readfirstlane((int)(threadIdx.x >> 6));
    int b_r = threadIdx.x >> 2, part = threadIdx.x & 3;
    int i0 = it * 8;
    float acc[10][4];
#pragma unroll
    for (int j = 0; j < 10; ++j)
#pragma unroll
        for (int o = 0; o < 4; ++o) acc[j][o] = 0.f;

    {
        const float4* lsrc = (const float4*)(L + (size_t)(b0 + b_r) * 11520 + i0 * 10 + part * 20);
#pragma unroll
        for (int q = 0; q < 5; ++q) {
            float4 t = lsrc[q]; int c = part * 20 + q * 4;
            LG[b_r][c] = t.x; LG[b_r][c + 1] = t.y; LG[b_r][c + 2] = t.z; LG[b_r][c + 3] = t.w;
        }
        const float4* usrc = (const float4*)(U + (size_t)(b0 + b_r) * 9216 + i0 * 8 + part * 16);
#pragma unroll
        for (int q = 0; q < 4; ++q) {
            float4 t = usrc[q]; int c = part * 16 + q * 4;
            UC[b_r][c] = t.x; UC[b_r][c + 1] = t.y; UC[b_r][c + 2] = t.z; UC[b_r][c + 3] = t.w;
        }
    }
    __syncthreads();
    for (int li = 0; li < 8; ++li) {
        float lg[10];
#pragma unroll
        for (int j = 0; j < 10; ++j) lg[j] = LG[b_l][li * 10 + j];
        float m = lg[0];
#pragma unroll
        for (int j = 1; j < 10; ++j) m = fmaxf(m, lg[j]);
        float e[10], ssum = 0.f;
#pragma unroll
        for (int j = 0; j < 10; ++j) { e[j] = __expf(lg[j] - m); ssum += e[j]; }
        float inv = 1.0f / ssum;
        float u8[8];
#pragma unroll
        for (int d = 0; d < 8; ++d) u8[d] = UC[b_l][li * 8 + d];
        const float* Wb = W + (size_t)(i0 + li) * 1280 + og * 4;
#pragma unroll
        for (int j = 0; j < 10; ++j) {
            float cj = e[j] * inv;
#pragma unroll
            for (int d = 0; d < 8; ++d) {
                const float* wp = Wb + (d * 10 + j) * 16;
                float f = cj * u8[d];
                acc[j][0] += f * wp[0]; acc[j][1] += f * wp[1];
                acc[j][2] += f * wp[2]; acc[j][3] += f * wp[3];
            }
        }
    }
    float* sp = SP + ((size_t)it * 256 + (b0 + b_l)) * 160 + og * 4;
#pragma unroll
    for (int j = 0; j < 10; ++j)
        *(float4*)(sp + j * 16) = make_float4(acc[j][0], acc[j][1], acc[j][2], acc[j][3]);
}

// ---------------- routing: reduce partials + squash -> v ----------------
__global__ __launch_bounds__(256) void k_route_v(const float* __restrict__ SP,
                                                 float* __restrict__ vout) {
    int n = blockIdx.x * 256 + threadIdx.x;  // 40960
    float ssum = 0.f;
    for (int t = 0; t < 144; ++t) ssum += SP[(size_t)t * 40960 + n];
    float sq = ssum * ssum;
    float tot = sq;
#pragma unroll
    for (int mask = 1; mask < 16; mask <<= 1) tot += __shfl_xor(tot, mask, 64);
    float scale = tot / ((1.0f + tot) * sqrtf(tot + 1e-8f));
    vout[n] = scale * ssum;
}

// ---------------- routing: agreement update b_logits += <u_hat, v> ----------------
// grid (144 i-tiles of 8, 4 b-tiles); block 256 = 64 b_lanes x 4 i-groups (2 i each)
__global__ __launch_bounds__(256) void k_route_agree(float* __restrict__ L,
                                                     const float* __restrict__ U,
                                                     const float* __restrict__ W,
                                                     const float* __restrict__ V) {
    __shared__ float LG[64][81];
    __shared__ float UC[64][65];
    __shared__ float VT[160][65];
    int it = blockIdx.x, bt = blockIdx.y;
    int b0 = bt * 64;
    int b_l = threadIdx.x & 63;
    int ig = __builtin_amdgcn_readfirstlane((int)(threadIdx.x >> 6));
    int b_r = threadIdx.x >> 2, part = threadIdx.x & 3;
    int i0 = it * 8;

    {   // stage v (all 160 jo), transposed
        const float4* vsrc = (const float4*)(V + (size_t)(b0 + b_r) * 160 + part * 40);
#pragma unroll
        for (int q = 0; q < 10; ++q) {
            float4 vv = vsrc[q];
            int jo = part * 40 + q * 4;
            VT[jo][b_r] = vv.x; VT[jo + 1][b_r] = vv.y; VT[jo + 2][b_r] = vv.z; VT[jo + 3][b_r] = vv.w;
        }
        const float4* lsrc = (const float4*)(L + (size_t)(b0 + b_r) * 11520 + i0 * 10 + part * 20);
#pragma unroll
        for (int q = 0; q < 5; ++q) {
            float4 t = lsrc[q]; int c = part * 20 + q * 4;
            LG[b_r][c] = t.x; LG[b_r][c + 1] = t.y; LG[b_r][c + 2] = t.z; LG[b_r][c + 3] = t.w;
        }
        const float4* usrc = (const float4*)(U + (size_t)(b0 + b_r) * 9216 + i0 * 8 + part * 16);
#pragma unroll
        for (int q = 0; q < 4; ++q) {
            float4 t = usrc[q]; int c = part * 16 + q * 4;
            UC[b_r][c] = t.x; UC[b_r][c + 1] = t.y; UC[b_r][c + 2] = t.z; UC[b_r][c + 3] = t.w;
        }
    }
    __syncthreads();
#pragma unroll
    for (int ii = 0; ii < 2; ++ii) {
        int ilocal = ig * 2 + ii;
        int i = i0 + ilocal;
        float u8[8];
#pragma unroll
        for (int d = 0; d < 8; ++d) u8[d] = UC[b_l][ilocal * 8 + d];
        const float* Wi = W + (size_t)i * 1280;
#pragma unroll
        for (int j = 0; j < 10; ++j) {
            float v16[16];
#pragma unroll
            for (int o = 0; o < 16; ++o) v16[o] = VT[j * 16 + o][b_l];
            float a = 0.f;
#pragma unroll
            for (int d = 0; d < 8; ++d) {
                const float* wp = Wi + d * 160 + j * 16;
                float wv = 0.f;
#pragma unroll
                for (int o = 0; o < 16; ++o) wv += wp[o] * v16[o];
                a += u8[d] * wv;
            }
            LG[b_l][ilocal * 10 + j] += a;
        }
    }
    __syncthreads();
    {
        float4* ldst = (float4*)(L + (size_t)(b0 + b_r) * 11520 + i0 * 10 + part * 20);
#pragma unroll
        for (int q = 0; q < 5; ++q) {
            int c = part * 20 + q * 4;
            ldst[q] = make_float4(LG[b_r][c], LG[b_r][c + 1], LG[b_r][c + 2], LG[b_r][c + 3]);
        }
    }
}

// ---------------- launcher ----------------
extern "C" void kernel_launch(void* const* d_in, const int* in_sizes, int n_in,
                              void* d_out, int out_size, void* d_ws, size_t ws_size,
                              hipStream_t stream) {
    (void)in_sizes; (void)n_in; (void)out_size; (void)ws_size;
    const float* x   = (const float*)d_in[0];
    const float* c1w = (const float*)d_in[1];
    const float* c1b = (const float*)d_in[2];
    const float* pcw = (const float*)d_in[3];
    const float* pcb = (const float*)d_in[4];
    const float* Wd  = (const float*)d_in[5];
    float* out = (float*)d_out;
    char* wsb  = (char*)d_ws;

    unsigned short* w4hi = (unsigned short*)(wsb + W4HI_OFF);
    unsigned short* w4lo = (unsigned short*)(wsb + W4LO_OFF);
    unsigned short* h2hi = (unsigned short*)(wsb + H2HI_OFF);
    unsigned short* h2lo = (unsigned short*)(wsb + H2LO_OFF);
    float* wT1 = (float*)(wsb + WT1_OFF);
    float* pp  = (float*)(wsb + PP_OFF);
    float* sp  = (float*)(wsb + SP_OFF);  // aliases h2hi (h2 dead after conv2)
    float* u   = (float*)(wsb + U_OFF);
    float* lg  = (float*)(wsb + LG_OFF);
    float* v   = (float*)(wsb + V_OFF);

    hipMemsetAsync(lg, 0, (size_t)256 * 1152 * 10 * sizeof(float), stream);
    hipMemsetAsync(pp, 0, (size_t)9216 * 256 * sizeof(float), stream);

    k_prep_w<<<dim3(256, 4), 256, 0, stream>>>(pcw, w4hi, w4lo);
    k_transpose_w1<<<81, 256, 0, stream>>>(c1w, wT1);
    k_conv1<<<dim3(10, 256), 256, 0, stream>>>(x, wT1, c1b, h2hi, h2lo);
    k_conv2_mfma<<<dim3(72, 2, 8), 256, 0, stream>>>(h2hi, h2lo, w4hi, w4lo, pp);
    k_sum_squash2<<<1152, 256, 0, stream>>>(pp, pcb, u);

    for (int itr = 0; itr < 3; ++itr) {
        k_route_s<<<dim3(144, 4), 256, 0, stream>>>(lg, u, Wd, sp);
        k_route_v<<<160, 256, 0, stream>>>(sp, (itr == 2) ? out : v);
        if (itr < 2)
            k_route_agree<<<dim3(144, 4), 256, 0, stream>>>(lg, u, Wd, v);
    }
}

// Round 5
// 588.803 us; speedup vs baseline: 4.9566x; 1.7434x over previous
//
#include <hip/hip_runtime.h>
#include <hip/hip_bf16.h>

// ---------------- problem constants ----------------
#define NI 1152
// conv2 GEMM view: M=9216 (b,py,px), N=256 (oc), K=82 taps (81 + 1 zero pad) x 256 ic

typedef __attribute__((ext_vector_type(8))) _Float16 f16x8;
typedef __attribute__((ext_vector_type(4))) float f32x4;
typedef __attribute__((ext_vector_type(8))) unsigned short u16x8;
typedef __attribute__((ext_vector_type(4))) unsigned short u16x4;

// ws layout (bytes). Phase-1 buffers (w4,h2,wT1,pp) alias under uhat (94.4MB):
static const size_t UHAT_OFF = 0;                        // bf16 1152*10*256*16 = 94,371,840
static const size_t W4_OFF   = 0;                        // f16 82*256*256 = 10,747,904
static const size_t H2_OFF   = 10747904UL;               // f16 256*400*256 = 52,428,800
static const size_t WT1_OFF  = 63176704UL;               // f32 81*256 = 82,944
static const size_t PP_OFF   = 63259648UL;               // f32 9216*256 = 9,437,184 (ends 72.7MB < 94.4MB)
static const size_t U_OFF    = 94371840UL;               // f32 u[i][b][d] = 9,437,184
static const size_t SP_OFF   = 103809024UL;              // f32 144*256*160 = 23,592,960
static const size_t L_OFF    = 127401984UL;              // f32 256*1152*10 = 11,796,480
static const size_t V_OFF    = 139198464UL;              // f32 256*160 = 163,840

__device__ __forceinline__ unsigned short f2bf(float x) {
    unsigned u = __builtin_bit_cast(unsigned, x);
    u += 0x7fffu + ((u >> 16) & 1u);
    return (unsigned short)(u >> 16);
}
__device__ __forceinline__ float bf2f(unsigned short h) {
    return __builtin_bit_cast(float, (unsigned)h << 16);
}
__device__ __forceinline__ void atomAddF(float* p, float v) {
    __hip_atomic_fetch_add(p, v, __ATOMIC_RELAXED, __HIP_MEMORY_SCOPE_AGENT);
}

#define GLD16(gsrc, ldst)                                                      \
    __builtin_amdgcn_global_load_lds(                                          \
        (__attribute__((address_space(1))) const void*)(gsrc),                 \
        (__attribute__((address_space(3))) void*)(ldst), 16, 0, 0)

// ---------------- weight prep: pc_w [oc][ic*81+tap] -> w4 f16 [tap][oc][ic] ----------------
__global__ __launch_bounds__(256) void k_prep_w(const float* __restrict__ pcw,
                                                _Float16* __restrict__ w4) {
    __shared__ float sl[5184];
    int oc  = blockIdx.x;       // 256
    int ic0 = blockIdx.y * 64;  // 4 chunks
    const float* src = pcw + (size_t)oc * 20736 + (size_t)ic0 * 81;
    for (int j = threadIdx.x; j < 5184; j += 256) sl[j] = src[j];
    __syncthreads();
    for (int t = threadIdx.x; t < 5184; t += 256) {
        int tap = t >> 6, i = t & 63;
        w4[(size_t)tap * 65536 + (size_t)oc * 256 + ic0 + i] = (_Float16)sl[i * 81 + tap];
    }
}

// conv1_w [oc][81] -> wT1 [t][oc]
__global__ void k_transpose_w1(const float* __restrict__ w, float* __restrict__ wT) {
    int t = blockIdx.x, oc = threadIdx.x;
    wT[t * 256 + oc] = w[oc * 81 + t];
}

// ---------------- conv1 + relu -> h2[b][y][x][oc] f16 ----------------
__global__ __launch_bounds__(256) void k_conv1(const float* __restrict__ x,
                                               const float* __restrict__ wT1,
                                               const float* __restrict__ bias,
                                               _Float16* __restrict__ h2) {
    int b  = blockIdx.y;    // 256
    int rp = blockIdx.x;    // 10 row-pairs
    int oc = threadIdx.x;   // 256
    int oy0 = rp * 2;
    const float* xb = x + (size_t)b * 784;
    float bv = bias[oc];
    float acc0[20], acc1[20];
#pragma unroll
    for (int i = 0; i < 20; ++i) { acc0[i] = bv; acc1[i] = bv; }
    for (int ky = 0; ky < 9; ++ky) {
        const float* r0 = xb + (oy0 + ky) * 28;
        const float* r1 = r0 + 28;
        float x0[28], x1[28];
#pragma unroll
        for (int c = 0; c < 28; ++c) { x0[c] = r0[c]; x1[c] = r1[c]; }
#pragma unroll
        for (int kx = 0; kx < 9; ++kx) {
            float w = wT1[(ky * 9 + kx) * 256 + oc];
#pragma unroll
            for (int px = 0; px < 20; ++px) {
                acc0[px] += x0[px + kx] * w;
                acc1[px] += x1[px + kx] * w;
            }
        }
    }
#pragma unroll
    for (int px = 0; px < 20; ++px) {
        size_t i0 = (size_t)((b * 20 + oy0) * 20 + px) * 256 + oc;
        size_t i1 = (size_t)((b * 20 + oy0 + 1) * 20 + px) * 256 + oc;
        h2[i0] = (_Float16)fmaxf(acc0[px], 0.f);
        h2[i1] = (_Float16)fmaxf(acc1[px], 0.f);
    }
}

// ---------------- primary caps conv: f16 MFMA implicit GEMM ----------------
// grid (72 mt, 2 nt, 8 ks); block 256 = 4 waves (2x2); 128x128 tile, BK=64 (2 taps/iter, 41 iters).
// LDS: 8 k-planes x 128 rows x 8 f16 per operand (16KB each). Atomic split-K epilogue.
__global__ __launch_bounds__(256, 4) void k_conv2_mfma(
    const _Float16* __restrict__ h2, const _Float16* __restrict__ w4,
    float* __restrict__ pp) {
    __shared__ _Float16 As[8192], Bs[8192];
    const int mt = blockIdx.x, nt = blockIdx.y, ks = blockIdx.z;
    const int l = threadIdx.x & 63;
    const int w = __builtin_amdgcn_readfirstlane((int)(threadIdx.x >> 6));
    const int wm = w >> 1, wn = w & 1;

    size_t gArow[2], gBrow[2];
#pragma unroll
    for (int q = 0; q < 2; ++q) {
        int m = mt * 128 + q * 64 + l;
        int b = m / 36, r = m % 36;
        int py = r / 6, px = r % 6;
        gArow[q] = ((size_t)(b * 20 + 2 * py) * 20 + 2 * px) * 256;
        gBrow[q] = (size_t)(nt * 128 + q * 64 + l) * 256;
    }
    const int ic0 = ks * 32;

    f32x4 acc[4][4];
    const f32x4 z = {0.f, 0.f, 0.f, 0.f};
#pragma unroll
    for (int mi = 0; mi < 4; ++mi)
#pragma unroll
        for (int ni = 0; ni < 4; ++ni) acc[mi][ni] = z;

    const int chrow = (l >> 4);               // k-chunk within a 32-k step
    const int fr = (l & 15);

    for (int it = 0; it < 41; ++it) {
        const int t0 = 2 * it, t1 = t0 + 1;
        const int tA1 = (t1 > 80) ? 80 : t1;  // clamp A address; B reads zero-padded tap 81
        // wave w stages planes 2w, 2w+1 (plane p: tap_local = p>>2, ic-chunk = p&3)
#pragma unroll
        for (int pi = 0; pi < 2; ++pi) {
            const int p = 2 * w + pi;
            const int tl = p >> 2, c = p & 3;
            const int t  = tl ? t1 : t0;
            const int tA = tl ? tA1 : t0;
            const size_t aoff = (size_t)((tA / 9) * 20 + (tA % 9)) * 256 + ic0 + c * 8;
            const size_t boff = (size_t)t * 65536 + ic0 + c * 8;
#pragma unroll
            for (int q = 0; q < 2; ++q) {
                GLD16(h2 + gArow[q] + aoff, As + p * 1024 + q * 512);
                GLD16(w4 + boff + gBrow[q], Bs + p * 1024 + q * 512);
            }
        }
        __syncthreads();
#pragma unroll
        for (int s = 0; s < 2; ++s) {
            const int pb = (s * 4 + chrow) * 1024;
            f16x8 a[4], b[4];
#pragma unroll
            for (int i = 0; i < 4; ++i) {
                a[i] = *(const f16x8*)(As + pb + (wm * 64 + i * 16 + fr) * 8);
                b[i] = *(const f16x8*)(Bs + pb + (wn * 64 + i * 16 + fr) * 8);
            }
#pragma unroll
            for (int mi = 0; mi < 4; ++mi)
#pragma unroll
                for (int ni = 0; ni < 4; ++ni)
                    acc[mi][ni] = __builtin_amdgcn_mfma_f32_16x16x32_f16(a[mi], b[ni], acc[mi][ni], 0, 0, 0);
        }
        __syncthreads();
    }
    // epilogue: D[m][n], m=(lane>>4)*4+reg, n=lane&15; atomic split-K reduce
    const int row0 = (l >> 4) * 4;
    const int ncol = l & 15;
#pragma unroll
    for (int mi = 0; mi < 4; ++mi)
#pragma unroll
        for (int ni = 0; ni < 4; ++ni) {
            int n = nt * 128 + wn * 64 + ni * 16 + ncol;
#pragma unroll
            for (int reg = 0; reg < 4; ++reg) {
                int m = mt * 128 + wm * 64 + mi * 16 + row0 + reg;
                atomAddF(&pp[(size_t)m * 256 + n], acc[mi][ni][reg]);
            }
        }
}

// ---------------- bias + primary squash -> u[i][b][d] ----------------
__global__ __launch_bounds__(256) void k_sum_squash2(const float* __restrict__ pp,
                                                     const float* __restrict__ bias,
                                                     float* __restrict__ u) {
    int m = blockIdx.x * 8 + (threadIdx.x >> 5);
    int cap = threadIdx.x & 31;
    const float* p0 = pp + (size_t)m * 256 + cap * 8;
    float s[8], sq = 0.f;
#pragma unroll
    for (int d = 0; d < 8; ++d) {
        float a = p0[d] + bias[cap * 8 + d];
        sq += a * a; s[d] = a;
    }
    float scale = sq / ((1.0f + sq) * sqrtf(sq + 1e-8f));
    int b = m / 36, r = m % 36;
    int i = cap * 36 + r;
    float* up = u + ((size_t)i * 256 + b) * 8;
    ((float4*)up)[0] = make_float4(scale * s[0], scale * s[1], scale * s[2], scale * s[3]);
    ((float4*)up)[1] = make_float4(scale * s[4], scale * s[5], scale * s[6], scale * s[7]);
}

// ---------------- build u_hat (bf16) [i][j][b][o] ----------------
__global__ __launch_bounds__(256) void k_build_uhat(const float* __restrict__ u,
                                                    const float* __restrict__ W,
                                                    unsigned short* __restrict__ UH) {
    __shared__ float Ws[1280];
    int i = blockIdx.x;  // 1152
    for (int t = threadIdx.x; t < 1280; t += 256) Ws[t] = W[(size_t)i * 1280 + t];
    __syncthreads();
    int b = threadIdx.x;  // 256
    const float* uptr = u + ((size_t)i * 256 + b) * 8;
    float u8[8];
    ((float4*)u8)[0] = ((const float4*)uptr)[0];
    ((float4*)u8)[1] = ((const float4*)uptr)[1];
#pragma unroll
    for (int j = 0; j < 10; ++j) {
        float o16[16];
#pragma unroll
        for (int o = 0; o < 16; ++o) o16[o] = 0.f;
#pragma unroll
        for (int d = 0; d < 8; ++d) {
            const float* wp = Ws + d * 160 + j * 16;
#pragma unroll
            for (int o = 0; o < 16; ++o) o16[o] += u8[d] * wp[o];
        }
        u16x8 h0, h1;
#pragma unroll
        for (int o = 0; o < 8; ++o) { h0[o] = f2bf(o16[o]); h1[o] = f2bf(o16[8 + o]); }
        unsigned short* dst = UH + ((size_t)(i * 10 + j) * 256 + b) * 16;
        *(u16x8*)dst = h0;
        *(u16x8*)(dst + 8) = h1;
    }
}

// ---------------- routing iter 0: s0 = 0.1 * sum_i u_hat (softmax of zeros) ----------------
__global__ __launch_bounds__(256) void k_route_s0(const unsigned short* __restrict__ UH,
                                                  float* __restrict__ SP) {
    int it = blockIdx.x, bt = blockIdx.y;
    int b0 = bt * 64, i0 = it * 8;
    int b_l = threadIdx.x & 63;
    int og = __builtin_amdgcn_readfirstlane((int)(threadIdx.x >> 6));
    float acc[10][4];
#pragma unroll
    for (int j = 0; j < 10; ++j)
#pragma unroll
        for (int o = 0; o < 4; ++o) acc[j][o] = 0.f;
    for (int li = 0; li < 8; ++li) {
        const unsigned short* up = UH + ((size_t)(i0 + li) * 10 * 256 + b0 + b_l) * 16 + og * 4;
#pragma unroll
        for (int j = 0; j < 10; ++j) {
            u16x4 t = *(const u16x4*)(up + j * 4096);
#pragma unroll
            for (int o = 0; o < 4; ++o) acc[j][o] += bf2f(t[o]);
        }
    }
    float* sp = SP + ((size_t)it * 256 + b0 + b_l) * 160 + og * 4;
#pragma unroll
    for (int j = 0; j < 10; ++j)
        *(float4*)(sp + j * 16) = make_float4(0.1f * acc[j][0], 0.1f * acc[j][1],
                                              0.1f * acc[j][2], 0.1f * acc[j][3]);
}

// ---------------- routing: s-partials (softmax of logits) ----------------
__global__ __launch_bounds__(256) void k_route_s(const float* __restrict__ L,
                                                 const unsigned short* __restrict__ UH,
                                                 float* __restrict__ SP) {
    __shared__ float LG[64][81];
    int it = blockIdx.x, bt = blockIdx.y;
    int b0 = bt * 64, i0 = it * 8;
    int b_l = threadIdx.x & 63;
    int og = __builtin_amdgcn_readfirstlane((int)(threadIdx.x >> 6));
    int b_r = threadIdx.x >> 2, part = threadIdx.x & 3;
    {
        const float4* lsrc = (const float4*)(L + (size_t)(b0 + b_r) * 11520 + i0 * 10 + part * 20);
#pragma unroll
        for (int q = 0; q < 5; ++q) {
            float4 t = lsrc[q]; int c = part * 20 + q * 4;
            LG[b_r][c] = t.x; LG[b_r][c + 1] = t.y; LG[b_r][c + 2] = t.z; LG[b_r][c + 3] = t.w;
        }
    }
    __syncthreads();
    float acc[10][4];
#pragma unroll
    for (int j = 0; j < 10; ++j)
#pragma unroll
        for (int o = 0; o < 4; ++o) acc[j][o] = 0.f;
    for (int li = 0; li < 8; ++li) {
        float lg[10];
#pragma unroll
        for (int j = 0; j < 10; ++j) lg[j] = LG[b_l][li * 10 + j];
        float m = lg[0];
#pragma unroll
        for (int j = 1; j < 10; ++j) m = fmaxf(m, lg[j]);
        float e[10], ssum = 0.f;
#pragma unroll
        for (int j = 0; j < 10; ++j) { e[j] = __expf(lg[j] - m); ssum += e[j]; }
        float inv = 1.0f / ssum;
        const unsigned short* up = UH + ((size_t)(i0 + li) * 10 * 256 + b0 + b_l) * 16 + og * 4;
#pragma unroll
        for (int j = 0; j < 10; ++j) {
            float cj = e[j] * inv;
            u16x4 t = *(const u16x4*)(up + j * 4096);
#pragma unroll
            for (int o = 0; o < 4; ++o) acc[j][o] += cj * bf2f(t[o]);
        }
    }
    float* sp = SP + ((size_t)it * 256 + b0 + b_l) * 160 + og * 4;
#pragma unroll
    for (int j = 0; j < 10; ++j)
        *(float4*)(sp + j * 16) = make_float4(acc[j][0], acc[j][1], acc[j][2], acc[j][3]);
}

// ---------------- routing: reduce partials + squash -> v ----------------
__global__ __launch_bounds__(256) void k_route_v(const float* __restrict__ SP,
                                                 float* __restrict__ vout) {
    int n = blockIdx.x * 256 + threadIdx.x;  // 40960
    float ssum = 0.f;
    for (int t = 0; t < 144; ++t) ssum += SP[(size_t)t * 40960 + n];
    float sq = ssum * ssum;
    float tot = sq;
#pragma unroll
    for (int mask = 1; mask < 16; mask <<= 1) tot += __shfl_xor(tot, mask, 64);
    float scale = tot / ((1.0f + tot) * sqrtf(tot + 1e-8f));
    vout[n] = scale * ssum;
}

// ---------------- routing: logits (+)= <u_hat, v> ----------------
// add=0: L = agreement (iter-0 logits are exactly zero); add=1: L += agreement
__global__ __launch_bounds__(256) void k_route_agree(float* __restrict__ L,
                                                     const unsigned short* __restrict__ UH,
                                                     const float* __restrict__ V,
                                                     int add) {
    __shared__ float VL[64][165];
    __shared__ float LG[64][81];
    int it = blockIdx.x, bt = blockIdx.y;
    int b0 = bt * 64, i0 = it * 8;
    int b_l = threadIdx.x & 63;
    int ig = __builtin_amdgcn_readfirstlane((int)(threadIdx.x >> 6));
    int b_r = threadIdx.x >> 2, part = threadIdx.x & 3;
    {
        const float4* vsrc = (const float4*)(V + (size_t)(b0 + b_r) * 160 + part * 40);
#pragma unroll
        for (int q = 0; q < 10; ++q) {
            float4 vv = vsrc[q]; int c = part * 40 + q * 4;
            VL[b_r][c] = vv.x; VL[b_r][c + 1] = vv.y; VL[b_r][c + 2] = vv.z; VL[b_r][c + 3] = vv.w;
        }
        if (add) {
            const float4* lsrc = (const float4*)(L + (size_t)(b0 + b_r) * 11520 + i0 * 10 + part * 20);
#pragma unroll
            for (int q = 0; q < 5; ++q) {
                float4 t = lsrc[q]; int c = part * 20 + q * 4;
                LG[b_r][c] = t.x; LG[b_r][c + 1] = t.y; LG[b_r][c + 2] = t.z; LG[b_r][c + 3] = t.w;
            }
        }
    }
    __syncthreads();
#pragma unroll
    for (int ii = 0; ii < 2; ++ii) {
        int il = ig * 2 + ii;
        int i = i0 + il;
        const unsigned short* up = UH + ((size_t)i * 10 * 256 + b0 + b_l) * 16;
#pragma unroll
        for (int j = 0; j < 10; ++j) {
            u16x8 ua = *(const u16x8*)(up + j * 4096);
            u16x8 ub = *(const u16x8*)(up + j * 4096 + 8);
            float a = 0.f;
#pragma unroll
            for (int o = 0; o < 8; ++o) a += bf2f(ua[o]) * VL[b_l][j * 16 + o];
#pragma unroll
            for (int o = 0; o < 8; ++o) a += bf2f(ub[o]) * VL[b_l][j * 16 + 8 + o];
            float base = add ? LG[b_l][il * 10 + j] : 0.f;
            LG[b_l][il * 10 + j] = base + a;
        }
    }
    __syncthreads();
    {
        float4* ldst = (float4*)(L + (size_t)(b0 + b_r) * 11520 + i0 * 10 + part * 20);
#pragma unroll
        for (int q = 0; q < 5; ++q) {
            int c = part * 20 + q * 4;
            ldst[q] = make_float4(LG[b_r][c], LG[b_r][c + 1], LG[b_r][c + 2], LG[b_r][c + 3]);
        }
    }
}

// ---------------- launcher ----------------
extern "C" void kernel_launch(void* const* d_in, const int* in_sizes, int n_in,
                              void* d_out, int out_size, void* d_ws, size_t ws_size,
                              hipStream_t stream) {
    (void)in_sizes; (void)n_in; (void)out_size; (void)ws_size;
    const float* x   = (const float*)d_in[0];
    const float* c1w = (const float*)d_in[1];
    const float* c1b = (const float*)d_in[2];
    const float* pcw = (const float*)d_in[3];
    const float* pcb = (const float*)d_in[4];
    const float* Wd  = (const float*)d_in[5];
    float* out = (float*)d_out;
    char* wsb  = (char*)d_ws;

    unsigned short* uh = (unsigned short*)(wsb + UHAT_OFF);
    _Float16* w4 = (_Float16*)(wsb + W4_OFF);
    _Float16* h2 = (_Float16*)(wsb + H2_OFF);
    float* wT1 = (float*)(wsb + WT1_OFF);
    float* pp  = (float*)(wsb + PP_OFF);
    float* u   = (float*)(wsb + U_OFF);
    float* sp  = (float*)(wsb + SP_OFF);
    float* lg  = (float*)(wsb + L_OFF);
    float* v   = (float*)(wsb + V_OFF);

    hipMemsetAsync(pp, 0, (size_t)9216 * 256 * sizeof(float), stream);
    hipMemsetAsync(w4 + (size_t)81 * 65536, 0, (size_t)65536 * sizeof(_Float16), stream);  // zero tap 81

    k_prep_w<<<dim3(256, 4), 256, 0, stream>>>(pcw, w4);
    k_transpose_w1<<<81, 256, 0, stream>>>(c1w, wT1);
    k_conv1<<<dim3(10, 256), 256, 0, stream>>>(x, wT1, c1b, h2);
    k_conv2_mfma<<<dim3(72, 2, 8), 256, 0, stream>>>(h2, w4, pp);
    k_sum_squash2<<<1152, 256, 0, stream>>>(pp, pcb, u);
    k_build_uhat<<<1152, 256, 0, stream>>>(u, Wd, uh);

    // iter 0: c = 0.1 exactly
    k_route_s0<<<dim3(144, 4), 256, 0, stream>>>(uh, sp);
    k_route_v<<<160, 256, 0, stream>>>(sp, v);
    k_route_agree<<<dim3(144, 4), 256, 0, stream>>>(lg, uh, v, 0);
    // iter 1
    k_route_s<<<dim3(144, 4), 256, 0, stream>>>(lg, uh, sp);
    k_route_v<<<160, 256, 0, stream>>>(sp, v);
    k_route_agree<<<dim3(144, 4), 256, 0, stream>>>(lg, uh, v, 1);
    // iter 2
    k_route_s<<<dim3(144, 4), 256, 0, stream>>>(lg, uh, sp);
    k_route_v<<<160, 256, 0, stream>>>(sp, out);
}

// Round 6
// 474.677 us; speedup vs baseline: 6.1483x; 1.2404x over previous
//
#include <hip/hip_runtime.h>
#include <hip/hip_bf16.h>

// ---------------- problem constants ----------------
#define NI 1152
// conv2 GEMM view: M=9216 reordered as (pos, b) = 36*256; N=256 (oc); K=82 taps x 256 ic

typedef __attribute__((ext_vector_type(8))) _Float16 f16x8;
typedef __attribute__((ext_vector_type(4))) float f32x4;
typedef __attribute__((ext_vector_type(8))) unsigned short u16x8;
typedef __attribute__((ext_vector_type(4))) unsigned short u16x4;

// ws layout (bytes). Phase-1 buffers (w5,h3,wT1,pp) alias under uhat (94.4MB):
static const size_t UHAT_OFF = 0;                        // bf16 1152*10*256*16 = 94,371,840
static const size_t W5_OFF   = 0;                        // f16 82*8*2*4*128*8 = 10,747,904 B
static const size_t H3_OFF   = 10747904UL;               // f16 8*20*20*4*256*8 = 52,428,800 B
static const size_t WT1_OFF  = 63176704UL;               // f32 81*256
static const size_t PP_OFF   = 63259648UL;               // f32 9216*256 (ends 72.7MB < 94.4MB)
static const size_t U_OFF    = 94371840UL;               // f32 u[i][b][d]
static const size_t SP_OFF   = 103809024UL;              // f32 144*256*160
static const size_t L_OFF    = 127401984UL;              // f32 256*1152*10
static const size_t V_OFF    = 139198464UL;              // f32 256*160

__device__ __forceinline__ unsigned short f2bf(float x) {
    unsigned u = __builtin_bit_cast(unsigned, x);
    u += 0x7fffu + ((u >> 16) & 1u);
    return (unsigned short)(u >> 16);
}
__device__ __forceinline__ float bf2f(unsigned short h) {
    return __builtin_bit_cast(float, (unsigned)h << 16);
}
__device__ __forceinline__ void atomAddF(float* p, float v) {
    __hip_atomic_fetch_add(p, v, __ATOMIC_RELAXED, __HIP_MEMORY_SCOPE_AGENT);
}

#define GLD16(gsrc, ldst)                                                      \
    __builtin_amdgcn_global_load_lds(                                          \
        (__attribute__((address_space(1))) const void*)(gsrc),                 \
        (__attribute__((address_space(3))) void*)(ldst), 16, 0, 0)

// ---------------- weight prep: pc_w [oc][ic*81+tap] -> w5 (Bs-image order) ----------------
// w5 linear: ((((tap*8+ks)*2+nt)*4 + p)*128 + row)*8 + icl,  oc=nt*128+row, ic=ks*32+p*8+icl
__global__ __launch_bounds__(256) void k_prep_w(const float* __restrict__ pcw,
                                                _Float16* __restrict__ w5) {
    __shared__ float sl[5184];
    int oc  = blockIdx.x;       // 256
    int ic0 = blockIdx.y * 64;  // 4 chunks
    const float* src = pcw + (size_t)oc * 20736 + (size_t)ic0 * 81;
    for (int j = threadIdx.x; j < 5184; j += 256) sl[j] = src[j];
    __syncthreads();
    int nt = oc >> 7, row = oc & 127;
    for (int t = threadIdx.x; t < 5184; t += 256) {
        int tap = t >> 6, i = t & 63;
        int ic = ic0 + i;
        int ks = ic >> 5, p = (ic >> 3) & 3, icl = ic & 7;
        w5[((size_t)(((tap * 8 + ks) * 2 + nt) * 4 + p) * 128 + row) * 8 + icl] =
            (_Float16)sl[i * 81 + tap];
    }
}

// conv1_w [oc][81] -> wT1 [t][oc]
__global__ void k_transpose_w1(const float* __restrict__ w, float* __restrict__ wT) {
    int t = blockIdx.x, oc = threadIdx.x;
    wT[t * 256 + oc] = w[oc * 81 + t];
}

// ---------------- conv1 + relu -> h3[ks][y][x][p][b][8] f16 (As-image order) ----------------
__global__ __launch_bounds__(256) void k_conv1(const float* __restrict__ x,
                                               const float* __restrict__ wT1,
                                               const float* __restrict__ bias,
                                               _Float16* __restrict__ h3) {
    __shared__ _Float16 hs[2][20][256];  // 20KB
    int b  = blockIdx.y;    // 256
    int rp = blockIdx.x;    // 10 row-pairs
    int oc = threadIdx.x;   // 256
    int oy0 = rp * 2;
    const float* xb = x + (size_t)b * 784;
    float bv = bias[oc];
    float acc0[20], acc1[20];
#pragma unroll
    for (int i = 0; i < 20; ++i) { acc0[i] = bv; acc1[i] = bv; }
    for (int ky = 0; ky < 9; ++ky) {
        const float* r0 = xb + (oy0 + ky) * 28;
        const float* r1 = r0 + 28;
        float x0[28], x1[28];
#pragma unroll
        for (int c = 0; c < 28; ++c) { x0[c] = r0[c]; x1[c] = r1[c]; }
#pragma unroll
        for (int kx = 0; kx < 9; ++kx) {
            float w = wT1[(ky * 9 + kx) * 256 + oc];
#pragma unroll
            for (int px = 0; px < 20; ++px) {
                acc0[px] += x0[px + kx] * w;
                acc1[px] += x1[px + kx] * w;
            }
        }
    }
#pragma unroll
    for (int px = 0; px < 20; ++px) {
        hs[0][px][oc] = (_Float16)fmaxf(acc0[px], 0.f);
        hs[1][px][oc] = (_Float16)fmaxf(acc1[px], 0.f);
    }
    __syncthreads();
    // write phase: 1280 chunks of 8 f16 = 16B each
    for (int cid = threadIdx.x; cid < 1280; cid += 256) {
        int kp = cid & 31;          // ks*4 + p
        int pos = cid >> 5;         // ry*20 + px
        int ry = pos / 20, px2 = pos % 20;
        int ks = kp >> 2, p = kp & 3;
        f16x8 val = *(const f16x8*)&hs[ry][px2][ks * 32 + p * 8];
        _Float16* dst = h3 + ((size_t)((ks * 400 + (oy0 + ry) * 20 + px2) * 4 + p) * 256 + b) * 8;
        *(f16x8*)dst = val;
    }
}

// ---------------- primary caps conv: f16 MFMA implicit GEMM, contiguous staging ----------------
// grid (72 mt = pos*2+bhalf, 2 nt, 8 ks); block 256 = 4 waves (2x2); 128x128 tile, BK=64.
// All GLD16s read contiguous 1KB spans (operands pre-packed in LDS-image order).
__global__ __launch_bounds__(256, 4) void k_conv2_mfma(
    const _Float16* __restrict__ h3, const _Float16* __restrict__ w5,
    float* __restrict__ pp) {
    __shared__ _Float16 As[8192], Bs[8192];
    const int mt = blockIdx.x, nt = blockIdx.y, ks = blockIdx.z;
    const int pos = mt >> 1, bhalf = mt & 1;
    const int py = pos / 6, px = pos % 6;
    const int l = threadIdx.x & 63;
    const int w = __builtin_amdgcn_readfirstlane((int)(threadIdx.x >> 6));
    const int wm = w >> 1, wn = w & 1;

    f32x4 acc[4][4];
    const f32x4 z = {0.f, 0.f, 0.f, 0.f};
#pragma unroll
    for (int mi = 0; mi < 4; ++mi)
#pragma unroll
        for (int ni = 0; ni < 4; ++ni) acc[mi][ni] = z;

    const int ch = (l >> 4) * 1024;           // k-chunk plane (shorts)
    const int am = (wm * 64 + (l & 15)) * 8;  // a-frag row offset within plane
    const int bn = (wn * 64 + (l & 15)) * 8;  // b-frag row offset within plane
    const int lds_off = w * 1024 + l * 8;

    for (int it = 0; it < 41; ++it) {
        const int t0 = 2 * it, t1 = t0 + 1;
        const int tA1 = (t1 > 80) ? 80 : t1;  // clamp A address; B tap 81 is zero-padded
#pragma unroll
        for (int tl = 0; tl < 2; ++tl) {
            const int tap  = tl ? t1 : t0;
            const int tapA = tl ? tA1 : t0;
            const int y = 2 * py + tapA / 9, xx = 2 * px + tapA % 9;
            // wave w stages plane w of both operands
            const _Float16* asrc = h3 + ((size_t)(ks * 400 + y * 20 + xx) * 4 + w) * 2048 +
                                   bhalf * 1024 + l * 8;
            const _Float16* bsrc = w5 + ((size_t)((tap * 8 + ks) * 2 + nt)) * 4096 + lds_off;
            GLD16(asrc,       As + tl * 4096 + lds_off);
            GLD16(asrc + 512, As + tl * 4096 + lds_off + 512);
            GLD16(bsrc,       Bs + tl * 4096 + lds_off);
            GLD16(bsrc + 512, Bs + tl * 4096 + lds_off + 512);
        }
        __syncthreads();
#pragma unroll
        for (int s = 0; s < 2; ++s) {
            const int pb = s * 4096 + ch;
            f16x8 a[4], b[4];
#pragma unroll
            for (int i = 0; i < 4; ++i) {
                a[i] = *(const f16x8*)(As + pb + am + i * 128);
                b[i] = *(const f16x8*)(Bs + pb + bn + i * 128);
            }
#pragma unroll
            for (int mi = 0; mi < 4; ++mi)
#pragma unroll
                for (int ni = 0; ni < 4; ++ni)
                    acc[mi][ni] = __builtin_amdgcn_mfma_f32_16x16x32_f16(a[mi], b[ni], acc[mi][ni], 0, 0, 0);
        }
        __syncthreads();
    }
    // epilogue: D[m][n], m=(lane>>4)*4+reg, n=lane&15; atomic split-K reduce
    const int row0 = (l >> 4) * 4;
    const int ncol = l & 15;
#pragma unroll
    for (int mi = 0; mi < 4; ++mi)
#pragma unroll
        for (int ni = 0; ni < 4; ++ni) {
            int n = nt * 128 + wn * 64 + ni * 16 + ncol;
#pragma unroll
            for (int reg = 0; reg < 4; ++reg) {
                int m = pos * 256 + bhalf * 128 + wm * 64 + mi * 16 + row0 + reg;
                atomAddF(&pp[(size_t)m * 256 + n], acc[mi][ni][reg]);
            }
        }
}

// ---------------- bias + primary squash -> u[i][b][d]  (pp m-order = pos*256+b) ----------------
__global__ __launch_bounds__(256) void k_sum_squash2(const float* __restrict__ pp,
                                                     const float* __restrict__ bias,
                                                     float* __restrict__ u) {
    int m = blockIdx.x * 8 + (threadIdx.x >> 5);
    int cap = threadIdx.x & 31;
    const float* p0 = pp + (size_t)m * 256 + cap * 8;
    float s[8], sq = 0.f;
#pragma unroll
    for (int d = 0; d < 8; ++d) {
        float a = p0[d] + bias[cap * 8 + d];
        sq += a * a; s[d] = a;
    }
    float scale = sq / ((1.0f + sq) * sqrtf(sq + 1e-8f));
    int pos = m >> 8, b = m & 255;
    int i = cap * 36 + pos;
    float* up = u + ((size_t)i * 256 + b) * 8;
    ((float4*)up)[0] = make_float4(scale * s[0], scale * s[1], scale * s[2], scale * s[3]);
    ((float4*)up)[1] = make_float4(scale * s[4], scale * s[5], scale * s[6], scale * s[7]);
}

// ---------------- build u_hat (bf16) [i][j][b][o] ----------------
__global__ __launch_bounds__(256) void k_build_uhat(const float* __restrict__ u,
                                                    const float* __restrict__ W,
                                                    unsigned short* __restrict__ UH) {
    __shared__ float Ws[1280];
    int i = blockIdx.x;  // 1152
    for (int t = threadIdx.x; t < 1280; t += 256) Ws[t] = W[(size_t)i * 1280 + t];
    __syncthreads();
    int b = threadIdx.x;  // 256
    const float* uptr = u + ((size_t)i * 256 + b) * 8;
    float u8[8];
    ((float4*)u8)[0] = ((const float4*)uptr)[0];
    ((float4*)u8)[1] = ((const float4*)uptr)[1];
#pragma unroll
    for (int j = 0; j < 10; ++j) {
        float o16[16];
#pragma unroll
        for (int o = 0; o < 16; ++o) o16[o] = 0.f;
#pragma unroll
        for (int d = 0; d < 8; ++d) {
            const float* wp = Ws + d * 160 + j * 16;
#pragma unroll
            for (int o = 0; o < 16; ++o) o16[o] += u8[d] * wp[o];
        }
        u16x8 h0, h1;
#pragma unroll
        for (int o = 0; o < 8; ++o) { h0[o] = f2bf(o16[o]); h1[o] = f2bf(o16[8 + o]); }
        unsigned short* dst = UH + ((size_t)(i * 10 + j) * 256 + b) * 16;
        *(u16x8*)dst = h0;
        *(u16x8*)(dst + 8) = h1;
    }
}

// ---------------- routing iter 0: s0 = 0.1 * sum_i u_hat ----------------
__global__ __launch_bounds__(256) void k_route_s0(const unsigned short* __restrict__ UH,
                                                  float* __restrict__ SP) {
    int it = blockIdx.x, bt = blockIdx.y;
    int b0 = bt * 64, i0 = it * 8;
    int b_l = threadIdx.x & 63;
    int og = __builtin_amdgcn_readfirstlane((int)(threadIdx.x >> 6));
    float acc[10][4];
#pragma unroll
    for (int j = 0; j < 10; ++j)
#pragma unroll
        for (int o = 0; o < 4; ++o) acc[j][o] = 0.f;
    for (int li = 0; li < 8; ++li) {
        const unsigned short* up = UH + ((size_t)(i0 + li) * 10 * 256 + b0 + b_l) * 16 + og * 4;
#pragma unroll
        for (int j = 0; j < 10; ++j) {
            u16x4 t = *(const u16x4*)(up + j * 4096);
#pragma unroll
            for (int o = 0; o < 4; ++o) acc[j][o] += bf2f(t[o]);
        }
    }
    float* sp = SP + ((size_t)it * 256 + b0 + b_l) * 160 + og * 4;
#pragma unroll
    for (int j = 0; j < 10; ++j)
        *(float4*)(sp + j * 16) = make_float4(0.1f * acc[j][0], 0.1f * acc[j][1],
                                              0.1f * acc[j][2], 0.1f * acc[j][3]);
}

// ---------------- routing: s-partials (softmax of logits) ----------------
__global__ __launch_bounds__(256) void k_route_s(const float* __restrict__ L,
                                                 const unsigned short* __restrict__ UH,
                                                 float* __restrict__ SP) {
    __shared__ float LG[64][81];
    int it = blockIdx.x, bt = blockIdx.y;
    int b0 = bt * 64, i0 = it * 8;
    int b_l = threadIdx.x & 63;
    int og = __builtin_amdgcn_readfirstlane((int)(threadIdx.x >> 6));
    int b_r = threadIdx.x >> 2, part = threadIdx.x & 3;
    {
        const float4* lsrc = (const float4*)(L + (size_t)(b0 + b_r) * 11520 + i0 * 10 + part * 20);
#pragma unroll
        for (int q = 0; q < 5; ++q) {
            float4 t = lsrc[q]; int c = part * 20 + q * 4;
            LG[b_r][c] = t.x; LG[b_r][c + 1] = t.y; LG[b_r][c + 2] = t.z; LG[b_r][c + 3] = t.w;
        }
    }
    __syncthreads();
    float acc[10][4];
#pragma unroll
    for (int j = 0; j < 10; ++j)
#pragma unroll
        for (int o = 0; o < 4; ++o) acc[j][o] = 0.f;
    for (int li = 0; li < 8; ++li) {
        float lg[10];
#pragma unroll
        for (int j = 0; j < 10; ++j) lg[j] = LG[b_l][li * 10 + j];
        float m = lg[0];
#pragma unroll
        for (int j = 1; j < 10; ++j) m = fmaxf(m, lg[j]);
        float e[10], ssum = 0.f;
#pragma unroll
        for (int j = 0; j < 10; ++j) { e[j] = __expf(lg[j] - m); ssum += e[j]; }
        float inv = 1.0f / ssum;
        const unsigned short* up = UH + ((size_t)(i0 + li) * 10 * 256 + b0 + b_l) * 16 + og * 4;
#pragma unroll
        for (int j = 0; j < 10; ++j) {
            float cj = e[j] * inv;
            u16x4 t = *(const u16x4*)(up + j * 4096);
#pragma unroll
            for (int o = 0; o < 4; ++o) acc[j][o] += cj * bf2f(t[o]);
        }
    }
    float* sp = SP + ((size_t)it * 256 + b0 + b_l) * 160 + og * 4;
#pragma unroll
    for (int j = 0; j < 10; ++j)
        *(float4*)(sp + j * 16) = make_float4(acc[j][0], acc[j][1], acc[j][2], acc[j][3]);
}

// ---------------- routing: reduce partials + squash -> v ----------------
__global__ __launch_bounds__(256) void k_route_v(const float* __restrict__ SP,
                                                 float* __restrict__ vout) {
    int n = blockIdx.x * 256 + threadIdx.x;  // 40960
    float ssum = 0.f;
    for (int t = 0; t < 144; ++t) ssum += SP[(size_t)t * 40960 + n];
    float sq = ssum * ssum;
    float tot = sq;
#pragma unroll
    for (int mask = 1; mask < 16; mask <<= 1) tot += __shfl_xor(tot, mask, 64);
    float scale = tot / ((1.0f + tot) * sqrtf(tot + 1e-8f));
    vout[n] = scale * ssum;
}

// ---------------- routing: logits (+)= <u_hat, v> ----------------
__global__ __launch_bounds__(256) void k_route_agree(float* __restrict__ L,
                                                     const unsigned short* __restrict__ UH,
                                                     const float* __restrict__ V,
                                                     int add) {
    __shared__ float VL[64][165];
    __shared__ float LG[64][81];
    int it = blockIdx.x, bt = blockIdx.y;
    int b0 = bt * 64, i0 = it * 8;
    int b_l = threadIdx.x & 63;
    int ig = __builtin_amdgcn_readfirstlane((int)(threadIdx.x >> 6));
    int b_r = threadIdx.x >> 2, part = threadIdx.x & 3;
    {
        const float4* vsrc = (const float4*)(V + (size_t)(b0 + b_r) * 160 + part * 40);
#pragma unroll
        for (int q = 0; q < 10; ++q) {
            float4 vv = vsrc[q]; int c = part * 40 + q * 4;
            VL[b_r][c] = vv.x; VL[b_r][c + 1] = vv.y; VL[b_r][c + 2] = vv.z; VL[b_r][c + 3] = vv.w;
        }
        if (add) {
            const float4* lsrc = (const float4*)(L + (size_t)(b0 + b_r) * 11520 + i0 * 10 + part * 20);
#pragma unroll
            for (int q = 0; q < 5; ++q) {
                float4 t = lsrc[q]; int c = part * 20 + q * 4;
                LG[b_r][c] = t.x; LG[b_r][c + 1] = t.y; LG[b_r][c + 2] = t.z; LG[b_r][c + 3] = t.w;
            }
        }
    }
    __syncthreads();
#pragma unroll
    for (int ii = 0; ii < 2; ++ii) {
        int il = ig * 2 + ii;
        int i = i0 + il;
        const unsigned short* up = UH + ((size_t)i * 10 * 256 + b0 + b_l) * 16;
#pragma unroll
        for (int j = 0; j < 10; ++j) {
            u16x8 ua = *(const u16x8*)(up + j * 4096);
            u16x8 ub = *(const u16x8*)(up + j * 4096 + 8);
            float a = 0.f;
#pragma unroll
            for (int o = 0; o < 8; ++o) a += bf2f(ua[o]) * VL[b_l][j * 16 + o];
#pragma unroll
            for (int o = 0; o < 8; ++o) a += bf2f(ub[o]) * VL[b_l][j * 16 + 8 + o];
            float base = add ? LG[b_l][il * 10 + j] : 0.f;
            LG[b_l][il * 10 + j] = base + a;
        }
    }
    __syncthreads();
    {
        float4* ldst = (float4*)(L + (size_t)(b0 + b_r) * 11520 + i0 * 10 + part * 20);
#pragma unroll
        for (int q = 0; q < 5; ++q) {
            int c = part * 20 + q * 4;
            ldst[q] = make_float4(LG[b_r][c], LG[b_r][c + 1], LG[b_r][c + 2], LG[b_r][c + 3]);
        }
    }
}

// ---------------- launcher ----------------
extern "C" void kernel_launch(void* const* d_in, const int* in_sizes, int n_in,
                              void* d_out, int out_size, void* d_ws, size_t ws_size,
                              hipStream_t stream) {
    (void)in_sizes; (void)n_in; (void)out_size; (void)ws_size;
    const float* x   = (const float*)d_in[0];
    const float* c1w = (const float*)d_in[1];
    const float* c1b = (const float*)d_in[2];
    const float* pcw = (const float*)d_in[3];
    const float* pcb = (const float*)d_in[4];
    const float* Wd  = (const float*)d_in[5];
    float* out = (float*)d_out;
    char* wsb  = (char*)d_ws;

    unsigned short* uh = (unsigned short*)(wsb + UHAT_OFF);
    _Float16* w5 = (_Float16*)(wsb + W5_OFF);
    _Float16* h3 = (_Float16*)(wsb + H3_OFF);
    float* wT1 = (float*)(wsb + WT1_OFF);
    float* pp  = (float*)(wsb + PP_OFF);
    float* u   = (float*)(wsb + U_OFF);
    float* sp  = (float*)(wsb + SP_OFF);
    float* lg  = (float*)(wsb + L_OFF);
    float* v   = (float*)(wsb + V_OFF);

    hipMemsetAsync(pp, 0, (size_t)9216 * 256 * sizeof(float), stream);
    hipMemsetAsync(w5 + (size_t)81 * 65536, 0, (size_t)65536 * sizeof(_Float16), stream);  // zero tap 81

    k_prep_w<<<dim3(256, 4), 256, 0, stream>>>(pcw, w5);
    k_transpose_w1<<<81, 256, 0, stream>>>(c1w, wT1);
    k_conv1<<<dim3(10, 256), 256, 0, stream>>>(x, wT1, c1b, h3);
    k_conv2_mfma<<<dim3(72, 2, 8), 256, 0, stream>>>(h3, w5, pp);
    k_sum_squash2<<<1152, 256, 0, stream>>>(pp, pcb, u);
    k_build_uhat<<<1152, 256, 0, stream>>>(u, Wd, uh);

    // iter 0: c = 0.1 exactly
    k_route_s0<<<dim3(144, 4), 256, 0, stream>>>(uh, sp);
    k_route_v<<<160, 256, 0, stream>>>(sp, v);
    k_route_agree<<<dim3(144, 4), 256, 0, stream>>>(lg, uh, v, 0);
    // iter 1
    k_route_s<<<dim3(144, 4), 256, 0, stream>>>(lg, uh, sp);
    k_route_v<<<160, 256, 0, stream>>>(sp, v);
    k_route_agree<<<dim3(144, 4), 256, 0, stream>>>(lg, uh, v, 1);
    // iter 2
    k_route_s<<<dim3(144, 4), 256, 0, stream>>>(lg, uh, sp);
    k_route_v<<<160, 256, 0, stream>>>(sp, out);
}

// Round 7
// 461.863 us; speedup vs baseline: 6.3189x; 1.0277x over previous
//
#include <hip/hip_runtime.h>
#include <hip/hip_bf16.h>

// ---------------- problem constants ----------------
#define NI 1152
// conv2 GEMM view: M=9216 as (pos,b)=36*256; N=256 (oc); K=81 taps x 256 ic

typedef __attribute__((ext_vector_type(8))) _Float16 f16x8;
typedef __attribute__((ext_vector_type(4))) float f32x4;
typedef __attribute__((ext_vector_type(8))) unsigned short u16x8;
typedef __attribute__((ext_vector_type(4))) unsigned short u16x4;

// ws layout (bytes). Phase-1 buffers (w6,h3,wT1,pp) alias under uhat (94.4MB):
static const size_t UHAT_OFF = 0;                        // bf16 1152*10*256*16 = 94,371,840
static const size_t W6_OFF   = 0;                        // f16 81*8*16*64*8 = 10,616,832 B
static const size_t H3_OFF   = 10747904UL;               // f16 8*400*4*256*8 = 52,428,800 B
static const size_t WT1_OFF  = 63176704UL;               // f32 81*256
static const size_t PP_OFF   = 63259648UL;               // f32 9216*256 (ends 72.7MB < 94.4MB)
static const size_t U_OFF    = 94371840UL;               // f32 u[i][b][d]
static const size_t SP_OFF   = 103809024UL;              // f32 144*256*160
static const size_t L_OFF    = 127401984UL;              // f32 256*1152*10
static const size_t V_OFF    = 139198464UL;              // f32 256*160

__device__ __forceinline__ unsigned short f2bf(float x) {
    unsigned u = __builtin_bit_cast(unsigned, x);
    u += 0x7fffu + ((u >> 16) & 1u);
    return (unsigned short)(u >> 16);
}
__device__ __forceinline__ float bf2f(unsigned short h) {
    return __builtin_bit_cast(float, (unsigned)h << 16);
}
__device__ __forceinline__ void atomAddF(float* p, float v) {
    __hip_atomic_fetch_add(p, v, __ATOMIC_RELAXED, __HIP_MEMORY_SCOPE_AGENT);
}

// ---------------- weight prep: pc_w [oc][ic*81+tap] -> w6 frag-linear ----------------
// w6 linear: (((tap*8+ks)*16 + og)*64 + lane)*8 + icl
//   og=oc>>4, fr=oc&15, lane=kch*16+fr, ic=ks*32+kch*8+icl
__global__ __launch_bounds__(256) void k_prep_w(const float* __restrict__ pcw,
                                                _Float16* __restrict__ w6) {
    __shared__ float sl[5184];
    int oc  = blockIdx.x;       // 256
    int ic0 = blockIdx.y * 64;  // 4 chunks
    const float* src = pcw + (size_t)oc * 20736 + (size_t)ic0 * 81;
    for (int j = threadIdx.x; j < 5184; j += 256) sl[j] = src[j];
    __syncthreads();
    int og = oc >> 4, fr = oc & 15;
    for (int t = threadIdx.x; t < 5184; t += 256) {
        int tap = t >> 6, i = t & 63;
        int ic = ic0 + i;
        int ks = ic >> 5, kch = (ic >> 3) & 3, icl = ic & 7;
        int lane = kch * 16 + fr;
        w6[(((size_t)(tap * 8 + ks) * 16 + og) * 64 + lane) * 8 + icl] =
            (_Float16)sl[i * 81 + tap];
    }
}

// conv1_w [oc][81] -> wT1 [t][oc]
__global__ void k_transpose_w1(const float* __restrict__ w, float* __restrict__ wT) {
    int t = blockIdx.x, oc = threadIdx.x;
    wT[t * 256 + oc] = w[oc * 81 + t];
}

// ---------------- conv1 + relu -> h3[ks][y][x][p][b][8] f16 ----------------
__global__ __launch_bounds__(256) void k_conv1(const float* __restrict__ x,
                                               const float* __restrict__ wT1,
                                               const float* __restrict__ bias,
                                               _Float16* __restrict__ h3) {
    __shared__ _Float16 hs[2][20][256];  // 20KB
    int b  = blockIdx.y;    // 256
    int rp = blockIdx.x;    // 10 row-pairs
    int oc = threadIdx.x;   // 256
    int oy0 = rp * 2;
    const float* xb = x + (size_t)b * 784;
    float bv = bias[oc];
    float acc0[20], acc1[20];
#pragma unroll
    for (int i = 0; i < 20; ++i) { acc0[i] = bv; acc1[i] = bv; }
    for (int ky = 0; ky < 9; ++ky) {
        const float* r0 = xb + (oy0 + ky) * 28;
        const float* r1 = r0 + 28;
        float x0[28], x1[28];
#pragma unroll
        for (int c = 0; c < 28; ++c) { x0[c] = r0[c]; x1[c] = r1[c]; }
#pragma unroll
        for (int kx = 0; kx < 9; ++kx) {
            float w = wT1[(ky * 9 + kx) * 256 + oc];
#pragma unroll
            for (int px = 0; px < 20; ++px) {
                acc0[px] += x0[px + kx] * w;
                acc1[px] += x1[px + kx] * w;
            }
        }
    }
#pragma unroll
    for (int px = 0; px < 20; ++px) {
        hs[0][px][oc] = (_Float16)fmaxf(acc0[px], 0.f);
        hs[1][px][oc] = (_Float16)fmaxf(acc1[px], 0.f);
    }
    __syncthreads();
    for (int cid = threadIdx.x; cid < 1280; cid += 256) {
        int kp = cid & 31;          // ks*4 + p
        int pos = cid >> 5;         // ry*20 + px
        int ry = pos / 20, px2 = pos % 20;
        int ks = kp >> 2, p = kp & 3;
        f16x8 val = *(const f16x8*)&hs[ry][px2][ks * 32 + p * 8];
        _Float16* dst = h3 + ((size_t)((ks * 400 + (oy0 + ry) * 20 + px2) * 4 + p) * 256 + b) * 8;
        *(f16x8*)dst = val;
    }
}

// ---------------- primary caps conv: LDS-free direct-register MFMA pipeline ----------------
// grid (72 mt=pos*2+bhalf, 2 nt, 8 ks); block 256 = 4 waves (2x2), wave tile 64x64.
// Both operands fragment-contiguous in global (A: 4x256B, B: 1KB per frag-load).
// 3-buffer distance-2 register pipeline; no LDS, no barriers; vmcnt never drains to 0.
__global__ __launch_bounds__(256, 2) void k_conv2_direct(
    const _Float16* __restrict__ h3, const _Float16* __restrict__ w6,
    float* __restrict__ pp) {
    const int mt = blockIdx.x, nt = blockIdx.y, ks = blockIdx.z;
    const int pos = mt >> 1, bhalf = mt & 1;
    const int py = pos / 6, px = pos % 6;
    const int l = threadIdx.x & 63;
    const int w = threadIdx.x >> 6;
    const int wm = w >> 1, wn = w & 1;
    const int p = l >> 4, fr = l & 15;

    // A lane base (element offsets, excl. tap window): + (y*20+x)*8192 + mi*128
    const _Float16* abase = h3 + (size_t)ks * 3276800 + p * 2048 +
                            (bhalf * 128 + wm * 64 + fr) * 8;
    // B lane base: + (tap*8+ks)*8192 + ni*512
    const _Float16* bbase = w6 + (nt * 8 + wn * 4) * 512 + l * 8;

    f16x8 a[3][4], b[3][4];
    f32x4 acc[4][4];
    const f32x4 z = {0.f, 0.f, 0.f, 0.f};
#pragma unroll
    for (int mi = 0; mi < 4; ++mi)
#pragma unroll
        for (int ni = 0; ni < 4; ++ni) acc[mi][ni] = z;

#define LOADAB(buf, tap)                                                       \
    do {                                                                       \
        const int _t = (tap);                                                  \
        const int _y = _t / 9, _x = _t - _y * 9;                               \
        const _Float16* _ab = abase + ((2 * py + _y) * 20 + (2 * px + _x)) * 8192; \
        a[buf][0] = *(const f16x8*)(_ab);                                      \
        a[buf][1] = *(const f16x8*)(_ab + 128);                                \
        a[buf][2] = *(const f16x8*)(_ab + 256);                                \
        a[buf][3] = *(const f16x8*)(_ab + 384);                                \
        const _Float16* _bb = bbase + (size_t)(_t * 8 + ks) * 8192;            \
        b[buf][0] = *(const f16x8*)(_bb);                                      \
        b[buf][1] = *(const f16x8*)(_bb + 512);                                \
        b[buf][2] = *(const f16x8*)(_bb + 1024);                               \
        b[buf][3] = *(const f16x8*)(_bb + 1536);                               \
    } while (0)

#define MFMA_ALL(buf)                                                          \
    do {                                                                       \
        _Pragma("unroll") for (int mi = 0; mi < 4; ++mi)                       \
            _Pragma("unroll") for (int ni = 0; ni < 4; ++ni)                   \
                acc[mi][ni] = __builtin_amdgcn_mfma_f32_16x16x32_f16(          \
                    a[buf][mi], b[buf][ni], acc[mi][ni], 0, 0, 0);             \
    } while (0)

    LOADAB(0, 0);
    LOADAB(1, 1);
    for (int k = 0; k < 27; ++k) {
        const int t0 = 3 * k;
        LOADAB(2, t0 + 2);           // t0+2 <= 80 always
        MFMA_ALL(0);
        if (t0 + 3 < 81) LOADAB(0, t0 + 3);
        MFMA_ALL(1);
        if (t0 + 4 < 81) LOADAB(1, t0 + 4);
        MFMA_ALL(2);
    }
#undef LOADAB
#undef MFMA_ALL

    // epilogue: D[m][n], m=(lane>>4)*4+reg, n=lane&15; atomic split-K reduce
    const int row0 = (l >> 4) * 4;
    const int ncol = l & 15;
#pragma unroll
    for (int mi = 0; mi < 4; ++mi)
#pragma unroll
        for (int ni = 0; ni < 4; ++ni) {
            int n = nt * 128 + wn * 64 + ni * 16 + ncol;
#pragma unroll
            for (int reg = 0; reg < 4; ++reg) {
                int m = pos * 256 + bhalf * 128 + wm * 64 + mi * 16 + row0 + reg;
                atomAddF(&pp[(size_t)m * 256 + n], acc[mi][ni][reg]);
            }
        }
}

// ---------------- bias + primary squash -> u[i][b][d]  (pp m-order = pos*256+b) ----------------
__global__ __launch_bounds__(256) void k_sum_squash2(const float* __restrict__ pp,
                                                     const float* __restrict__ bias,
                                                     float* __restrict__ u) {
    int m = blockIdx.x * 8 + (threadIdx.x >> 5);
    int cap = threadIdx.x & 31;
    const float* p0 = pp + (size_t)m * 256 + cap * 8;
    float s[8], sq = 0.f;
#pragma unroll
    for (int d = 0; d < 8; ++d) {
        float a = p0[d] + bias[cap * 8 + d];
        sq += a * a; s[d] = a;
    }
    float scale = sq / ((1.0f + sq) * sqrtf(sq + 1e-8f));
    int pos = m >> 8, b = m & 255;
    int i = cap * 36 + pos;
    float* up = u + ((size_t)i * 256 + b) * 8;
    ((float4*)up)[0] = make_float4(scale * s[0], scale * s[1], scale * s[2], scale * s[3]);
    ((float4*)up)[1] = make_float4(scale * s[4], scale * s[5], scale * s[6], scale * s[7]);
}

// ---------------- build u_hat (bf16) [i][j][b][o] ----------------
__global__ __launch_bounds__(256) void k_build_uhat(const float* __restrict__ u,
                                                    const float* __restrict__ W,
                                                    unsigned short* __restrict__ UH) {
    __shared__ float Ws[1280];
    int i = blockIdx.x;  // 1152
    for (int t = threadIdx.x; t < 1280; t += 256) Ws[t] = W[(size_t)i * 1280 + t];
    __syncthreads();
    int b = threadIdx.x;  // 256
    const float* uptr = u + ((size_t)i * 256 + b) * 8;
    float u8[8];
    ((float4*)u8)[0] = ((const float4*)uptr)[0];
    ((float4*)u8)[1] = ((const float4*)uptr)[1];
#pragma unroll
    for (int j = 0; j < 10; ++j) {
        float o16[16];
#pragma unroll
        for (int o = 0; o < 16; ++o) o16[o] = 0.f;
#pragma unroll
        for (int d = 0; d < 8; ++d) {
            const float* wp = Ws + d * 160 + j * 16;
#pragma unroll
            for (int o = 0; o < 16; ++o) o16[o] += u8[d] * wp[o];
        }
        u16x8 h0, h1;
#pragma unroll
        for (int o = 0; o < 8; ++o) { h0[o] = f2bf(o16[o]); h1[o] = f2bf(o16[8 + o]); }
        unsigned short* dst = UH + ((size_t)(i * 10 + j) * 256 + b) * 16;
        *(u16x8*)dst = h0;
        *(u16x8*)(dst + 8) = h1;
    }
}

// ---------------- routing iter 0: s0 = 0.1 * sum_i u_hat ----------------
__global__ __launch_bounds__(256) void k_route_s0(const unsigned short* __restrict__ UH,
                                                  float* __restrict__ SP) {
    int it = blockIdx.x, bt = blockIdx.y;
    int b0 = bt * 64, i0 = it * 8;
    int b_l = threadIdx.x & 63;
    int og = __builtin_amdgcn_readfirstlane((int)(threadIdx.x >> 6));
    float acc[10][4];
#pragma unroll
    for (int j = 0; j < 10; ++j)
#pragma unroll
        for (int o = 0; o < 4; ++o) acc[j][o] = 0.f;
    for (int li = 0; li < 8; ++li) {
        const unsigned short* up = UH + ((size_t)(i0 + li) * 10 * 256 + b0 + b_l) * 16 + og * 4;
#pragma unroll
        for (int j = 0; j < 10; ++j) {
            u16x4 t = *(const u16x4*)(up + j * 4096);
#pragma unroll
            for (int o = 0; o < 4; ++o) acc[j][o] += bf2f(t[o]);
        }
    }
    float* sp = SP + ((size_t)it * 256 + b0 + b_l) * 160 + og * 4;
#pragma unroll
    for (int j = 0; j < 10; ++j)
        *(float4*)(sp + j * 16) = make_float4(0.1f * acc[j][0], 0.1f * acc[j][1],
                                              0.1f * acc[j][2], 0.1f * acc[j][3]);
}

// ---------------- fused routing: logits (+)= <u_hat,v>; softmax; s-partials ----------------
// grid (144,4); block 256. add=0: L := agreement (prior logits zero). storeL: write L back.
__global__ __launch_bounds__(256) void k_route_as(float* __restrict__ L,
                                                  const unsigned short* __restrict__ UH,
                                                  const float* __restrict__ V,
                                                  float* __restrict__ SP,
                                                  int add, int storeL) {
    __shared__ float VL[64][165];
    __shared__ float LG[64][81];
    int it = blockIdx.x, bt = blockIdx.y;
    int b0 = bt * 64, i0 = it * 8;
    int b_l = threadIdx.x & 63;
    int ig = __builtin_amdgcn_readfirstlane((int)(threadIdx.x >> 6));
    int b_r = threadIdx.x >> 2, part = threadIdx.x & 3;
    {
        const float4* vsrc = (const float4*)(V + (size_t)(b0 + b_r) * 160 + part * 40);
#pragma unroll
        for (int q = 0; q < 10; ++q) {
            float4 vv = vsrc[q]; int c = part * 40 + q * 4;
            VL[b_r][c] = vv.x; VL[b_r][c + 1] = vv.y; VL[b_r][c + 2] = vv.z; VL[b_r][c + 3] = vv.w;
        }
        if (add) {
            const float4* lsrc = (const float4*)(L + (size_t)(b0 + b_r) * 11520 + i0 * 10 + part * 20);
#pragma unroll
            for (int q = 0; q < 5; ++q) {
                float4 t = lsrc[q]; int c = part * 20 + q * 4;
                LG[b_r][c] = t.x; LG[b_r][c + 1] = t.y; LG[b_r][c + 2] = t.z; LG[b_r][c + 3] = t.w;
            }
        }
    }
    __syncthreads();
    // agreement phase: thread group ig handles 2 i's
#pragma unroll
    for (int ii = 0; ii < 2; ++ii) {
        int il = ig * 2 + ii;
        int i = i0 + il;
        const unsigned short* up = UH + ((size_t)i * 10 * 256 + b0 + b_l) * 16;
#pragma unroll
        for (int j = 0; j < 10; ++j) {
            u16x8 ua = *(const u16x8*)(up + j * 4096);
            u16x8 ub = *(const u16x8*)(up + j * 4096 + 8);
            float a = 0.f;
#pragma unroll
            for (int o = 0; o < 8; ++o) a += bf2f(ua[o]) * VL[b_l][j * 16 + o];
#pragma unroll
            for (int o = 0; o < 8; ++o) a += bf2f(ub[o]) * VL[b_l][j * 16 + 8 + o];
            float base = add ? LG[b_l][il * 10 + j] : 0.f;
            LG[b_l][il * 10 + j] = base + a;
        }
    }
    __syncthreads();
    if (storeL) {
        float4* ldst = (float4*)(L + (size_t)(b0 + b_r) * 11520 + i0 * 10 + part * 20);
#pragma unroll
        for (int q = 0; q < 5; ++q) {
            int c = part * 20 + q * 4;
            ldst[q] = make_float4(LG[b_r][c], LG[b_r][c + 1], LG[b_r][c + 2], LG[b_r][c + 3]);
        }
    }
    // s phase: softmax of fresh logits, accumulate c * u_hat (og = ig reuse)
    float acc[10][4];
#pragma unroll
    for (int j = 0; j < 10; ++j)
#pragma unroll
        for (int o = 0; o < 4; ++o) acc[j][o] = 0.f;
    for (int li = 0; li < 8; ++li) {
        float lg[10];
#pragma unroll
        for (int j = 0; j < 10; ++j) lg[j] = LG[b_l][li * 10 + j];
        float m = lg[0];
#pragma unroll
        for (int j = 1; j < 10; ++j) m = fmaxf(m, lg[j]);
        float e[10], ssum = 0.f;
#pragma unroll
        for (int j = 0; j < 10; ++j) { e[j] = __expf(lg[j] - m); ssum += e[j]; }
        float inv = 1.0f / ssum;
        const unsigned short* up = UH + ((size_t)(i0 + li) * 10 * 256 + b0 + b_l) * 16 + ig * 4;
#pragma unroll
        for (int j = 0; j < 10; ++j) {
            float cj = e[j] * inv;
            u16x4 t = *(const u16x4*)(up + j * 4096);
#pragma unroll
            for (int o = 0; o < 4; ++o) acc[j][o] += cj * bf2f(t[o]);
        }
    }
    float* sp = SP + ((size_t)it * 256 + b0 + b_l) * 160 + ig * 4;
#pragma unroll
    for (int j = 0; j < 10; ++j)
        *(float4*)(sp + j * 16) = make_float4(acc[j][0], acc[j][1], acc[j][2], acc[j][3]);
}

// ---------------- routing: reduce partials + squash -> v ----------------
__global__ __launch_bounds__(256) void k_route_v(const float* __restrict__ SP,
                                                 float* __restrict__ vout) {
    int n = blockIdx.x * 256 + threadIdx.x;  // 40960
    float ssum = 0.f;
    for (int t = 0; t < 144; ++t) ssum += SP[(size_t)t * 40960 + n];
    float sq = ssum * ssum;
    float tot = sq;
#pragma unroll
    for (int mask = 1; mask < 16; mask <<= 1) tot += __shfl_xor(tot, mask, 64);
    float scale = tot / ((1.0f + tot) * sqrtf(tot + 1e-8f));
    vout[n] = scale * ssum;
}

// ---------------- launcher ----------------
extern "C" void kernel_launch(void* const* d_in, const int* in_sizes, int n_in,
                              void* d_out, int out_size, void* d_ws, size_t ws_size,
                              hipStream_t stream) {
    (void)in_sizes; (void)n_in; (void)out_size; (void)ws_size;
    const float* x   = (const float*)d_in[0];
    const float* c1w = (const float*)d_in[1];
    const float* c1b = (const float*)d_in[2];
    const float* pcw = (const float*)d_in[3];
    const float* pcb = (const float*)d_in[4];
    const float* Wd  = (const float*)d_in[5];
    float* out = (float*)d_out;
    char* wsb  = (char*)d_ws;

    unsigned short* uh = (unsigned short*)(wsb + UHAT_OFF);
    _Float16* w6 = (_Float16*)(wsb + W6_OFF);
    _Float16* h3 = (_Float16*)(wsb + H3_OFF);
    float* wT1 = (float*)(wsb + WT1_OFF);
    float* pp  = (float*)(wsb + PP_OFF);
    float* u   = (float*)(wsb + U_OFF);
    float* sp  = (float*)(wsb + SP_OFF);
    float* lg  = (float*)(wsb + L_OFF);
    float* v   = (float*)(wsb + V_OFF);

    hipMemsetAsync(pp, 0, (size_t)9216 * 256 * sizeof(float), stream);

    k_prep_w<<<dim3(256, 4), 256, 0, stream>>>(pcw, w6);
    k_transpose_w1<<<81, 256, 0, stream>>>(c1w, wT1);
    k_conv1<<<dim3(10, 256), 256, 0, stream>>>(x, wT1, c1b, h3);
    k_conv2_direct<<<dim3(72, 2, 8), 256, 0, stream>>>(h3, w6, pp);
    k_sum_squash2<<<1152, 256, 0, stream>>>(pp, pcb, u);
    k_build_uhat<<<1152, 256, 0, stream>>>(u, Wd, uh);

    // iter 0: c = 0.1 exactly
    k_route_s0<<<dim3(144, 4), 256, 0, stream>>>(uh, sp);
    k_route_v<<<160, 256, 0, stream>>>(sp, v);
    // iter 1 (fused agree+softmax+s); logits were zero -> add=0, store for iter 2
    k_route_as<<<dim3(144, 4), 256, 0, stream>>>(lg, uh, v, sp, 0, 1);
    k_route_v<<<160, 256, 0, stream>>>(sp, v);
    // iter 2 (fused); last use of logits -> no store
    k_route_as<<<dim3(144, 4), 256, 0, stream>>>(lg, uh, v, sp, 1, 0);
    k_route_v<<<160, 256, 0, stream>>>(sp, out);
}